// Round 22
// baseline (365.773 us; speedup 1.0000x reference)
//
#include <hip/hip_runtime.h>
#include <hip/hip_bf16.h>
#include <math.h>

#define NSEQ   10000
#define NPAD   10240
#define PADR   240
#define HEADS  8
#define DH     64
#define LM     256
#define LFAC   40
#define DMODEL 512
#define DQK    256
#define OUTSZ  20001
#define NSPLIT 16
#define KCH    128

typedef __attribute__((ext_vector_type(8))) short bf16x8;
typedef __attribute__((ext_vector_type(4))) float f32x4;
#define MFMA16(a,b,c) __builtin_amdgcn_mfma_f32_16x16x32_bf16(a,b,c,0,0,0)

typedef __attribute__((address_space(1))) const unsigned char gconst_t;
typedef __attribute__((address_space(3))) unsigned char lds_t;
#define GLD16(gp, lp) __builtin_amdgcn_global_load_lds((gconst_t*)(gp), (lds_t*)(lp), 16, 0, 0)

__device__ __forceinline__ float b2f(ushort u) {
    return __uint_as_float(((unsigned)u) << 16);
}
__device__ __forceinline__ ushort f2b(float f) {
    unsigned u = __float_as_uint(f);
    unsigned r = (u + 0x7FFFu + ((u >> 16) & 1u)) >> 16;
    return (ushort)r;
}
__device__ __forceinline__ unsigned fenc(float f) {
    unsigned u = __float_as_uint(f);
    return (u & 0x80000000u) ? ~u : (u | 0x80000000u);
}
__device__ __forceinline__ float fdec(unsigned k) {
    return __uint_as_float((k & 0x80000000u) ? (k & 0x7FFFFFFFu) : ~k);
}
__device__ __forceinline__ int swz8(int bid, int nwg) {
    int q = nwg >> 3, r = nwg & 7;
    int x = bid & 7, idx = bid >> 3;
    int start = (x < r) ? x * (q + 1) : r * (q + 1) + (x - r) * q;
    return start + idx;
}
__device__ __forceinline__ f32x4 tr4(f32x4 v, int p) {
    f32x4 u, w;
    float s, r;
    s = (p & 1) ? v[0] : v[1]; r = __shfl_xor(s, 1);
    u[0] = (p & 1) ? r : v[0]; u[1] = (p & 1) ? v[1] : r;
    s = (p & 1) ? v[2] : v[3]; r = __shfl_xor(s, 1);
    u[2] = (p & 1) ? r : v[2]; u[3] = (p & 1) ? v[3] : r;
    s = (p & 2) ? u[0] : u[2]; r = __shfl_xor(s, 2);
    w[0] = (p & 2) ? r : u[0]; w[2] = (p & 2) ? u[2] : r;
    s = (p & 2) ? u[1] : u[3]; r = __shfl_xor(s, 2);
    w[1] = (p & 2) ? r : u[1]; w[3] = (p & 2) ? u[3] : r;
    return w;
}

// ---------------------------------------------------------------- cvt + wtrans + init
__global__ __launch_bounds__(256)
void cvtw_k(const float* __restrict__ in, ushort* __restrict__ out,
            float* __restrict__ outbuf, const float* __restrict__ fcb,
            unsigned int* __restrict__ mx,
            const float* __restrict__ w_qkv, const float* __restrict__ w_out,
            const float* __restrict__ wq, const float* __restrict__ wk,
            const float* __restrict__ wv_w,
            ushort* __restrict__ wqkvT, ushort* __restrict__ woutT,
            ushort* __restrict__ wqkT)
{
    __shared__ float tile[32][33];
    int bid = blockIdx.x;
    if (bid < 5000) {
        int i = bid * 256 + threadIdx.x;
        float4 v = ((const float4*)in)[i];
        ushort4 u; u.x = f2b(v.x); u.y = f2b(v.y); u.z = f2b(v.z); u.w = f2b(v.w);
        ((ushort4*)out)[i] = u;
        if (i == 0) {
            outbuf[0] = fcb[0];
            mx[0] = 0u; mx[1] = 0u;
            mx[2] = 0u;
            ((float*)mx)[3] = 0.f;
        }
        if (i >= 1 && i <= NSEQ) outbuf[i] = 0.f;
        if (i >= NSEQ + 1 && i < OUTSZ) outbuf[i] = 1.0f;
    } else {
        int wb = bid - 5000;
        int g0 = (wb % 96) * 32, r0 = (wb / 96) * 32;
        const float* src; ushort* outp; int C; int lc0;
        if (g0 < 1536)      { src = w_qkv; outp = wqkvT;                      C = 1536; lc0 = g0; }
        else if (g0 < 2048) { src = w_out; outp = woutT;                      C = 512;  lc0 = g0 - 1536; }
        else if (g0 < 2304) { src = wq;    outp = wqkT;                       C = 256;  lc0 = g0 - 2048; }
        else if (g0 < 2560) { src = wk;    outp = wqkT + 256*512;             C = 256;  lc0 = g0 - 2304; }
        else                { src = wv_w;  outp = wqkvT + (size_t)1536*512;   C = 512;  lc0 = g0 - 2560; }
        int tx = threadIdx.x & 31, ty = threadIdx.x >> 5;
        for (int i = ty; i < 32; i += 8) tile[i][tx] = src[(size_t)(r0 + i) * C + lc0 + tx];
        __syncthreads();
        for (int i = ty; i < 32; i += 8) outp[(size_t)(lc0 + i) * 512 + r0 + tx] = f2b(tile[tx][i]);
    }
}

// ---------------------------------------------------------------- big MFMA GEMM (BM=128, BN=TN)
template<int MODE, int TN>
__global__ __launch_bounds__(256)
void mgemm(const ushort* __restrict__ A, const ushort* __restrict__ Bt,
           int Mlog, int N, int K, int padr, int nbx,
           void* __restrict__ P0, void* __restrict__ P1, void* __restrict__ P2,
           void* __restrict__ P3, void* __restrict__ P4,
           const float* __restrict__ bias, const ushort* __restrict__ extra)
{
    constexpr int NF = TN / 32;
    constexpr int BSB = TN * 64;
    __shared__ __align__(16) char As[2 * 8192];
    __shared__ __align__(16) char Bs[2 * BSB];
    const int tid = threadIdx.x;
    const int l = tid & 63, w = tid >> 6;
    const int wm = w >> 1, wn = w & 1;
    const int wk_ = swz8(blockIdx.x, gridDim.x);
    const int row0 = (wk_ / nbx) * 128, col0 = (wk_ % nbx) * TN;
    const int lr = l & 15, lg = l >> 4;
    const bool slow = (MODE == 0) && (row0 < padr);
    const int NT = K >> 5;
    f32x4 acc[4][NF];
    #pragma unroll
    for (int i = 0; i < 4; ++i)
        #pragma unroll
        for (int j = 0; j < NF; ++j) acc[i][j] = (f32x4){0.f, 0.f, 0.f, 0.f};

    auto stage = [&](int bf, int t) {
        int k0 = t << 5;
        if (!slow) {
            #pragma unroll
            for (int c = 0; c < 2; ++c) {
                int q = w * 2 + c;
                int row = q * 16 + (l >> 2);
                GLD16(A + (size_t)(row0 + row - padr) * K + k0 + (l & 3) * 8,
                      As + bf * 8192 + q * 1024);
            }
            if (TN == 128) {
                #pragma unroll
                for (int c = 0; c < 2; ++c) {
                    int q = w * 2 + c;
                    int row = q * 16 + (l >> 2);
                    GLD16(Bt + (size_t)(col0 + row) * K + k0 + (l & 3) * 8,
                          Bs + bf * BSB + q * 1024);
                }
            } else {
                int row = w * 16 + (l >> 2);
                GLD16(Bt + (size_t)(col0 + row) * K + k0 + (l & 3) * 8,
                      Bs + bf * BSB + w * 1024);
            }
        } else {
            #pragma unroll
            for (int c = 0; c < 2; ++c) {
                int gidx = c * 256 + tid;
                int row = gidx >> 2, gr = gidx & 3;
                int phys = row0 + row - padr;
                uint4 v = {0, 0, 0, 0};
                if (phys >= 0 && phys < Mlog - padr)
                    v = *(const uint4*)(A + (size_t)phys * K + k0 + gr * 8);
                *(uint4*)(As + bf * 8192 + gidx * 16) = v;
            }
            if (TN == 128) {
                #pragma unroll
                for (int c = 0; c < 2; ++c) {
                    int gidx = c * 256 + tid;
                    int row = gidx >> 2, gr = gidx & 3;
                    *(uint4*)(Bs + bf * BSB + gidx * 16) =
                        *(const uint4*)(Bt + (size_t)(col0 + row) * K + k0 + gr * 8);
                }
            } else {
                int row = tid >> 2, gr = tid & 3;
                *(uint4*)(Bs + bf * BSB + tid * 16) =
                    *(const uint4*)(Bt + (size_t)(col0 + row) * K + k0 + gr * 8);
            }
        }
    };

    int cur = 0;
    stage(0, 0);
    __syncthreads();
    for (int t = 0; t < NT; ++t) {
        if (t + 1 < NT) stage(cur ^ 1, t + 1);
        const char* Ab = As + cur * 8192;
        const char* Bb = Bs + cur * BSB;
        bf16x8 af[4];
        #pragma unroll
        for (int mf = 0; mf < 4; ++mf)
            af[mf] = *(const bf16x8*)(Ab + (wm * 64 + mf * 16 + lr) * 64 + lg * 16);
        #pragma unroll
        for (int nf = 0; nf < NF; ++nf) {
            bf16x8 bfr = *(const bf16x8*)(Bb + (wn * (TN / 2) + nf * 16 + lr) * 64 + lg * 16);
            #pragma unroll
            for (int mf = 0; mf < 4; ++mf)
                acc[mf][nf] = MFMA16(af[mf], bfr, acc[mf][nf]);
        }
        __syncthreads();
        cur ^= 1;
    }

    const int p = lr & 3;
    #pragma unroll
    for (int mf = 0; mf < 4; ++mf)
    #pragma unroll
    for (int nf = 0; nf < NF; ++nf) {
        int cb   = col0 + wn * (TN / 2) + nf * 16 + (lr & 12);
        int rowT = row0 + wm * 64 + mf * 16 + lg * 4 + p;
        if (MODE == 0) {
            int c = col0 + wn * (TN / 2) + nf * 16 + lr;
            if ((c >> 9) == 2) {
                int hh = (c >> 6) & 7;
                int kt  = (row0 + wm * 64 + mf * 16 + lg * 4) >> 5;
                int lgp = ((mf * 2) + (lg >> 1)) & 3;
                int lanep = lr + lgp * 16;
                int e0 = (lg & 1) * 4;
                ushort4 pk;
                pk.x = f2b(acc[mf][nf][0]); pk.y = f2b(acc[mf][nf][1]);
                pk.z = f2b(acc[mf][nf][2]); pk.w = f2b(acc[mf][nf][3]);
                *(ushort4*)&((ushort*)P3)[(((size_t)hh * (NPAD/32) + kt) * 4 + (nf & 3)) * 512
                                          + lanep * 8 + e0] = pk;
            }
            int t = cb >> 9;
            f32x4 v = acc[mf][nf];
            if (t == 0) { v[0] *= 0.125f; v[1] *= 0.125f; v[2] *= 0.125f; v[3] *= 0.125f; }
            f32x4 wv = tr4(v, p);
            ushort4 pk;
            pk.x = f2b(wv[0]); pk.y = f2b(wv[1]); pk.z = f2b(wv[2]); pk.w = f2b(wv[3]);
            if (t < 3) {
                int hh = (cb >> 6) & 7, d0 = cb & 63;
                ushort* dst = (t == 0) ? (ushort*)P0 : (t == 1) ? (ushort*)P1 : (ushort*)P2;
                *(ushort4*)&dst[((size_t)hh * NPAD + rowT) * DH + d0] = pk;
            } else {
                int phys = rowT - PADR;
                if (phys >= 0)
                    *(ushort4*)&((ushort*)P4)[(size_t)phys * DMODEL + (cb & 511)] = pk;
            }
        } else if (MODE == 1) {
            f32x4 wv = tr4(acc[mf][nf], p);
            if (rowT < Mlog) {
                float4 bi = *(const float4*)(bias + cb);
                ushort4 bg = *(const ushort4*)(extra + (size_t)rowT * N + cb);
                float o0 = wv[0] + bi.x + b2f(bg.x), o1 = wv[1] + bi.y + b2f(bg.y);
                float o2 = wv[2] + bi.z + b2f(bg.z), o3 = wv[3] + bi.w + b2f(bg.w);
                ushort4 pk; pk.x = f2b(o0); pk.y = f2b(o1); pk.z = f2b(o2); pk.w = f2b(o3);
                *(ushort4*)&((ushort*)P1)[(size_t)rowT * N + cb] = pk;
            }
        } else if (MODE == 6) {
            f32x4 wv = tr4(acc[mf][nf], p);
            if (rowT < Mlog) {
                ushort4 pk;
                pk.x = f2b(wv[0]); pk.y = f2b(wv[1]); pk.z = f2b(wv[2]); pk.w = f2b(wv[3]);
                if (cb < 256)
                    *(ushort4*)&((ushort*)P0)[(size_t)rowT * 256 + cb] = pk;
                else
                    *(ushort4*)&((ushort*)P1)[(size_t)rowT * 256 + (cb - 256)] = pk;
            }
        }
    }
}

// ---------------------------------------------------------------- pinv one-shot-K GEMM
// row-split: 16 output rows per block (grid y = 16), 2+ blocks/CU for latency overlap
template<bool PLAIN, bool BCI, bool WPK>
__global__ __launch_bounds__(256)
void pinv_k(const ushort* __restrict__ A, const ushort* __restrict__ Bt,
            int N, float cval, float scale,
            ushort* __restrict__ P0, ushort* __restrict__ P1)
{
    __shared__ __align__(16) char smem[40960];
    char* As = smem;                 // 16 rows x 512B = 8KB
    char* Bs = smem + 8192;          // 64 rows x 512B = 32KB
    const int tid = threadIdx.x, l = tid & 63, w = tid >> 6;
    const int lr = l & 15, lg = l >> 4;
    const int col0 = blockIdx.x * 64, row0 = blockIdx.y * 16, h = blockIdx.z;
    const ushort* Ab = A + (size_t)h * 65536;
    const ushort* Btb = Bt + (size_t)h * ((size_t)N * 256);
    {
        int row = tid >> 4, seg = (tid & 15) * 32;
        const uint4* sa = (const uint4*)(Ab + (size_t)(row0 + row) * 256) + (tid & 15) * 2;
        #pragma unroll
        for (int e = 0; e < 2; ++e) {
            int off = (row * 512 + seg + e * 16) ^ ((row & 7) << 4);
            *(uint4*)(As + off) = sa[e];
        }
    }
    {
        int row = tid >> 2, seg = (tid & 3) * 128;
        const uint4* sb = (const uint4*)(Btb + (size_t)(col0 + row) * 256) + (tid & 3) * 8;
        int gn = col0 + row;
        #pragma unroll
        for (int e = 0; e < 8; ++e) {
            int off = (row * 512 + seg + e * 16) ^ ((row & 7) << 4);
            uint4 vb = sb[e];
            if (BCI) {
                union { uint4 u; ushort s[8]; } t; t.u = vb;
                int gk0 = (seg >> 1) + e * 8;
                #pragma unroll
                for (int j = 0; j < 8; ++j)
                    t.s[j] = f2b(((gn == gk0 + j) ? cval : 0.f) - b2f(t.s[j]));
                vb = t.u;
            }
            *(uint4*)(Bs + off) = vb;
        }
    }
    __syncthreads();
    f32x4 acc = (f32x4){0.f, 0.f, 0.f, 0.f};
    #pragma unroll
    for (int ks = 0; ks < 8; ++ks) {
        bf16x8 af = *(const bf16x8*)(As + ((lr * 512 + ks * 64 + lg * 16) ^ ((lr & 7) << 4)));
        int br = w * 16 + lr;
        bf16x8 bf = *(const bf16x8*)(Bs + ((br * 512 + ks * 64 + lg * 16) ^ ((br & 7) << 4)));
        acc = MFMA16(af, bf, acc);
    }
    {
        int r0v = row0 + lg * 4;
        int c = col0 + w * 16 + lr;
        if (PLAIN) {
            #pragma unroll
            for (int i = 0; i < 4; ++i)
                P0[(size_t)h * 256 * N + (size_t)(r0v + i) * N + c] = f2b(acc[i] * scale);
        }
        ushort4 pk;
        pk.x = f2b(acc[0] * scale); pk.y = f2b(acc[1] * scale);
        pk.z = f2b(acc[2] * scale); pk.w = f2b(acc[3] * scale);
        if (WPK) {
            int off = (((c >> 4) * 8 + (r0v >> 5)) << 9) + (((r0v >> 3) & 3) << 7)
                    + ((c & 15) << 3) + (r0v & 4);
            *(ushort4*)&P1[(size_t)h * 16384 + off] = pk;
        } else {
            *(ushort4*)&P1[(size_t)h * ((size_t)N * 256) + (size_t)c * 256 + r0v] = pk;
        }
    }
}

// ---------------------------------------------------------------- NS L2: batched pair (row-split)
// blockIdx.y in [0,32): which = y>>4 (0: Qt = (P@(7I-P))^T ; 1: V1 = Z@P plain)
__global__ __launch_bounds__(256)
void ns2_k(const ushort* __restrict__ P, const ushort* __restrict__ Pt,
           const ushort* __restrict__ Z,
           ushort* __restrict__ Qt, ushort* __restrict__ V1)
{
    __shared__ __align__(16) char smem[40960];
    char* As = smem;
    char* Bs = smem + 8192;
    const int tid = threadIdx.x, l = tid & 63, w = tid >> 6;
    const int lr = l & 15, lg = l >> 4;
    const int col0 = blockIdx.x * 64;
    const int which = blockIdx.y >> 4;
    const int row0 = (blockIdx.y & 15) * 16;
    const int h = blockIdx.z;
    const ushort* Ab = (which ? Z : P) + (size_t)h * 65536;
    const ushort* Btb = Pt + (size_t)h * 65536;
    {
        int row = tid >> 4, seg = (tid & 15) * 32;
        const uint4* sa = (const uint4*)(Ab + (size_t)(row0 + row) * 256) + (tid & 15) * 2;
        #pragma unroll
        for (int e = 0; e < 2; ++e) {
            int off = (row * 512 + seg + e * 16) ^ ((row & 7) << 4);
            *(uint4*)(As + off) = sa[e];
        }
    }
    {
        int row = tid >> 2, seg = (tid & 3) * 128;
        const uint4* sb = (const uint4*)(Btb + (size_t)(col0 + row) * 256) + (tid & 3) * 8;
        int gn = col0 + row;
        #pragma unroll
        for (int e = 0; e < 8; ++e) {
            int off = (row * 512 + seg + e * 16) ^ ((row & 7) << 4);
            uint4 vb = sb[e];
            if (which == 0) {
                union { uint4 u; ushort s[8]; } t; t.u = vb;
                int gk0 = (seg >> 1) + e * 8;
                #pragma unroll
                for (int j = 0; j < 8; ++j)
                    t.s[j] = f2b(((gn == gk0 + j) ? 7.f : 0.f) - b2f(t.s[j]));
                vb = t.u;
            }
            *(uint4*)(Bs + off) = vb;
        }
    }
    __syncthreads();
    f32x4 acc = (f32x4){0.f, 0.f, 0.f, 0.f};
    #pragma unroll
    for (int ks = 0; ks < 8; ++ks) {
        bf16x8 af = *(const bf16x8*)(As + ((lr * 512 + ks * 64 + lg * 16) ^ ((lr & 7) << 4)));
        int br = w * 16 + lr;
        bf16x8 bf = *(const bf16x8*)(Bs + ((br * 512 + ks * 64 + lg * 16) ^ ((br & 7) << 4)));
        acc = MFMA16(af, bf, acc);
    }
    {
        int r0v = row0 + lg * 4;
        int c = col0 + w * 16 + lr;
        if (which == 0) {
            ushort4 pk;
            pk.x = f2b(acc[0]); pk.y = f2b(acc[1]);
            pk.z = f2b(acc[2]); pk.w = f2b(acc[3]);
            *(ushort4*)&Qt[(size_t)h * 65536 + (size_t)c * 256 + r0v] = pk;
        } else {
            #pragma unroll
            for (int i = 0; i < 4; ++i)
                V1[(size_t)h * 65536 + (size_t)(r0v + i) * 256 + c] = f2b(acc[i]);
        }
    }
}

// ---------------------------------------------------------------- NS L3 (row-split)
__global__ __launch_bounds__(256)
void ns3_k(const ushort* __restrict__ V1, const ushort* __restrict__ Qt,
           const ushort* __restrict__ Z,
           ushort* __restrict__ Zn, ushort* __restrict__ Znt)
{
    __shared__ __align__(16) char smem[40960];
    char* As = smem;
    char* Bs = smem + 8192;
    const int tid = threadIdx.x, l = tid & 63, w = tid >> 6;
    const int lr = l & 15, lg = l >> 4;
    const int col0 = blockIdx.x * 64, row0 = blockIdx.y * 16, h = blockIdx.z;
    const ushort* Ab = V1 + (size_t)h * 65536;
    const ushort* Btb = Qt + (size_t)h * 65536;
    {
        int row = tid >> 4, seg = (tid & 15) * 32;
        const uint4* sa = (const uint4*)(Ab + (size_t)(row0 + row) * 256) + (tid & 15) * 2;
        #pragma unroll
        for (int e = 0; e < 2; ++e) {
            int off = (row * 512 + seg + e * 16) ^ ((row & 7) << 4);
            *(uint4*)(As + off) = sa[e];
        }
    }
    {
        int row = tid >> 2, seg = (tid & 3) * 128;
        const uint4* sb = (const uint4*)(Btb + (size_t)(col0 + row) * 256) + (tid & 3) * 8;
        #pragma unroll
        for (int e = 0; e < 8; ++e) {
            int off = (row * 512 + seg + e * 16) ^ ((row & 7) << 4);
            *(uint4*)(Bs + off) = sb[e];
        }
    }
    __syncthreads();
    f32x4 acc = (f32x4){0.f, 0.f, 0.f, 0.f};
    #pragma unroll
    for (int ks = 0; ks < 8; ++ks) {
        bf16x8 af = *(const bf16x8*)(As + ((lr * 512 + ks * 64 + lg * 16) ^ ((lr & 7) << 4)));
        int br = w * 16 + lr;
        bf16x8 bf = *(const bf16x8*)(Bs + ((br * 512 + ks * 64 + lg * 16) ^ ((br & 7) << 4)));
        acc = MFMA16(af, bf, acc);
    }
    {
        int r0v = row0 + lg * 4;
        int c = col0 + w * 16 + lr;
        ushort4 pk;
        #pragma unroll
        for (int i = 0; i < 4; ++i) {
            size_t idx = (size_t)h * 65536 + (size_t)(r0v + i) * 256 + c;
            float o = 0.25f * acc[i] + 3.25f * b2f(Z[idx]) - 3.75f * b2f(V1[idx]);
            ushort u = f2b(o);
            Zn[idx] = u;
            ((ushort*)&pk)[i] = u;
        }
        *(ushort4*)&Znt[(size_t)h * 65536 + (size_t)c * 256 + r0v] = pk;
    }
}

// ---------------------------------------------------------------- conv + landmarks merged
__global__ __launch_bounds__(256)
void landconv_k(const ushort* __restrict__ Qb, const ushort* __restrict__ Kb,
                const ushort* __restrict__ Vb, const float* __restrict__ cw,
                ushort* __restrict__ OBc,
                ushort* __restrict__ QLb, ushort* __restrict__ KLb,
                ushort* __restrict__ KLpk)
{
    int bid = blockIdx.x;
    if (bid < 5000) {
        int idx = bid * 256 + threadIdx.x;
        int ro = idx >> 7, c4 = idx & 127;
        int h = c4 >> 4, dq = (c4 & 15) * 4;
        int i = ro + PADR;
        float a0 = 0, a1 = 0, a2 = 0, a3 = 0;
        #pragma unroll
        for (int tt = 0; tt < 33; ++tt) {
            int src = i + tt - 16;
            if (src < NPAD) {
                float wv = cw[h * 33 + tt];
                ushort4 u = *(const ushort4*)(Vb + ((size_t)h * NPAD + src) * DH + dq);
                a0 += wv * b2f(u.x); a1 += wv * b2f(u.y);
                a2 += wv * b2f(u.z); a3 += wv * b2f(u.w);
            }
        }
        ushort4 o; o.x = f2b(a0); o.y = f2b(a1); o.z = f2b(a2); o.w = f2b(a3);
        *(ushort4*)&OBc[(size_t)ro * DMODEL + h * DH + dq] = o;
    } else {
        int gidx = (bid - 5000) * 4 + (threadIdx.x >> 6);
        int d = threadIdx.x & 63;
        bool isK = gidx >= HEADS * LM;
        int b = isK ? gidx - HEADS * LM : gidx;
        int hh = b >> 8, j = b & 255;
        const ushort* p = (isK ? Kb : Qb) + ((size_t)hh * NPAD + (size_t)j * LFAC) * DH + d;
        float s = 0.f;
        #pragma unroll
        for (int t = 0; t < LFAC; ++t) s += b2f(p[t * DH]);
        ushort u = f2b(s * (1.f / LFAC));
        (isK ? KLb : QLb)[((size_t)hh * LM + j) * DH + d] = u;
        if (isK) {
            int nf = j >> 4, lr = j & 15;
            int ks = d >> 5, lg = (d >> 3) & 3, e = d & 7;
            KLpk[(((size_t)hh * 16 + nf) * 2 + ks) * 512 + (lg * 16 + lr) * 8 + e] = u;
        }
    }
}

// ---------------------------------------------------------------- attn2 via MFMA
__global__ __launch_bounds__(256)
void attn2m_k(const ushort* __restrict__ QLb, const ushort* __restrict__ KLpk,
              ushort* __restrict__ X2b)
{
    __shared__ __align__(16) char smem[40960];
    char*   Qs  = smem;
    ushort* KLs = (ushort*)(smem + 8192);
    const int tid = threadIdx.x, l = tid & 63, w = tid >> 6;
    const int h = blockIdx.y, i0 = blockIdx.x * 64;
    const int lr = l & 15, lg = l >> 4;
    {
        int row = tid >> 2;
        int seg = (tid & 3) * 32;
        const uint4* src = (const uint4*)(QLb + ((size_t)h * LM + i0 + row) * DH) + (tid & 3) * 2;
        uint4 v0 = src[0], v1 = src[1];
        int sw = (row & 7) << 4;
        *(uint4*)(Qs + row * 128 + (seg ^ sw)) = v0;
        *(uint4*)(Qs + row * 128 + ((seg + 16) ^ sw)) = v1;
    }
    {
        const uint4* src = (const uint4*)(KLpk + (size_t)h * 16384) + tid;
        uint4* dst = (uint4*)KLs + tid;
        #pragma unroll
        for (int e = 0; e < 8; ++e) dst[e * 256] = src[e * 256];
    }
    __syncthreads();

    f32x4 s[16];
    #pragma unroll
    for (int nf = 0; nf < 16; ++nf) s[nf] = (f32x4){0.f, 0.f, 0.f, 0.f};
    #pragma unroll
    for (int ks = 0; ks < 2; ++ks) {
        int qrow = w * 16 + lr;
        bf16x8 a = *(const bf16x8*)(Qs + qrow * 128 +
                                    ((ks * 64 + lg * 16) ^ ((qrow & 7) << 4)));
        #pragma unroll
        for (int nf = 0; nf < 16; ++nf) {
            bf16x8 b = *(const bf16x8*)&KLs[((nf * 2 + ks) * 64 + l) * 8];
            s[nf] = MFMA16(a, b, s[nf]);
        }
    }
    float inv_[4];
    #pragma unroll
    for (int i = 0; i < 4; ++i) {
        float m = s[0][i];
        #pragma unroll
        for (int nf = 1; nf < 16; ++nf) m = fmaxf(m, s[nf][i]);
        m = fmaxf(m, __shfl_xor(m, 1)); m = fmaxf(m, __shfl_xor(m, 2));
        m = fmaxf(m, __shfl_xor(m, 4)); m = fmaxf(m, __shfl_xor(m, 8));
        float sum = 0.f;
        #pragma unroll
        for (int nf = 0; nf < 16; ++nf) {
            float e = __expf(s[nf][i] - m); s[nf][i] = e; sum += e;
        }
        sum += __shfl_xor(sum, 1); sum += __shfl_xor(sum, 2);
        sum += __shfl_xor(sum, 4); sum += __shfl_xor(sum, 8);
        inv_[i] = 1.f / sum;
    }
    const int p = lr & 3;
    #pragma unroll
    for (int nf = 0; nf < 16; ++nf) {
        f32x4 v = s[nf];
        v[0] *= inv_[0]; v[1] *= inv_[1]; v[2] *= inv_[2]; v[3] *= inv_[3];
        f32x4 wv = tr4(v, p);
        int rowT = i0 + w * 16 + lg * 4 + p;
        int cb = nf * 16 + (lr & 12);
        ushort4 pk;
        pk.x = f2b(wv[0]); pk.y = f2b(wv[1]); pk.z = f2b(wv[2]); pk.w = f2b(wv[3]);
        *(ushort4*)&X2b[((size_t)h * LM + rowT) * LM + cb] = pk;
    }
}

// only column-sum max needed (row sums of softmax == 1)
__global__ __launch_bounds__(256)
void colrow_k(const ushort* __restrict__ X2b, unsigned int* __restrict__ mx)
{
    int h = blockIdx.x, t = threadIdx.x;
    const ushort* x = X2b + (size_t)h * LM * LM;
    float rs = 0.f;
    for (int i = 0; i < LM; ++i) rs += fabsf(b2f(x[(size_t)i * LM + t]));
    __shared__ float r2[256];
    r2[t] = rs; __syncthreads();
    for (int s = 128; s > 0; s >>= 1) {
        if (t < s) r2[t] = fmaxf(r2[t], r2[t + s]);
        __syncthreads();
    }
    if (t == 0) atomicMax(&mx[1], __float_as_uint(r2[0]));
}

__global__ void zinit_k(const ushort* __restrict__ X2b, const float* __restrict__ mxf,
                        ushort* __restrict__ Z, ushort* __restrict__ Zt)
{
    int i = blockIdx.x, h = blockIdx.y, j = threadIdx.x;
    float scale = 1.f / mxf[1];
    float x = b2f(X2b[((size_t)h * LM + i) * LM + j]) * scale;
    ushort u = f2b(x);
    Z[((size_t)h * LM + j) * LM + i] = u;
    Zt[((size_t)h * LM + i) * LM + j] = u;
}

// ---------------------------------------------------------------- attn3: flash MFMA
__global__ __launch_bounds__(256)
void attn3_fa(const ushort* __restrict__ QLb, const ushort* __restrict__ Kb,
              const ushort* __restrict__ VtPk,
              float* __restrict__ Opart, float* __restrict__ Mpart,
              float* __restrict__ Lpart)
{
    __shared__ __align__(16) char smem[9216 + 18432];
    ushort* Qs = (ushort*)smem;
    ushort* Ks = (ushort*)(smem + 9216);
    ushort* Ps = (ushort*)(smem + 9216);
    const int tid = threadIdx.x, l = tid & 63, wv = tid >> 6;
    const int split = blockIdx.x, qt = blockIdx.y, h = blockIdx.z;
    const int lr = l & 15, lg = l >> 4;
    {
        int row = tid >> 2, seg = (tid & 3) * 16;
        const uint4* src = (const uint4*)(QLb + ((size_t)h * LM + qt * 64 + row) * DH + seg);
        *(uint4*)&Qs[row * 72 + seg] = src[0];
        *(uint4*)&Qs[row * 72 + seg + 8] = src[1];
    }
    f32x4 o[4];
    float m_[4], l_[4];
    #pragma unroll
    for (int nf = 0; nf < 4; ++nf) o[nf] = (f32x4){0.f, 0.f, 0.f, 0.f};
    #pragma unroll
    for (int i = 0; i < 4; ++i) { m_[i] = -INFINITY; l_[i] = 0.f; }
    const int k0base = split * (NPAD / NSPLIT);
    for (int ch = 0; ch < NPAD / NSPLIT / KCH; ++ch) {
        int kg0 = k0base + ch * KCH;
        __syncthreads();
        {
            int row = tid >> 1, half = (tid & 1) * 32;
            const uint4* src = (const uint4*)(Kb + ((size_t)h * NPAD + kg0 + row) * DH + half);
            #pragma unroll
            for (int e = 0; e < 4; ++e) *(uint4*)&Ks[row * 72 + half + e * 8] = src[e];
        }
        __syncthreads();
        f32x4 s[8];
        #pragma unroll
        for (int nf = 0; nf < 8; ++nf) s[nf] = (f32x4){0.f, 0.f, 0.f, 0.f};
        #pragma unroll
        for (int ks = 0; ks < 2; ++ks) {
            bf16x8 a = *(const bf16x8*)&Qs[(wv * 16 + lr) * 72 + ks * 32 + lg * 8];
            #pragma unroll
            for (int nf = 0; nf < 8; ++nf) {
                bf16x8 b = *(const bf16x8*)&Ks[(nf * 16 + lr) * 72 + ks * 32 + lg * 8];
                s[nf] = MFMA16(a, b, s[nf]);
            }
        }
        float scl[4];
        #pragma unroll
        for (int i = 0; i < 4; ++i) {
            float mx = s[0][i];
            #pragma unroll
            for (int nf = 1; nf < 8; ++nf) mx = fmaxf(mx, s[nf][i]);
            mx = fmaxf(mx, __shfl_xor(mx, 1)); mx = fmaxf(mx, __shfl_xor(mx, 2));
            mx = fmaxf(mx, __shfl_xor(mx, 4)); mx = fmaxf(mx, __shfl_xor(mx, 8));
            float mn = fmaxf(m_[i], mx);
            float sum = 0.f;
            #pragma unroll
            for (int nf = 0; nf < 8; ++nf) {
                float e = __expf(s[nf][i] - mn); s[nf][i] = e; sum += e;
            }
            sum += __shfl_xor(sum, 1); sum += __shfl_xor(sum, 2);
            sum += __shfl_xor(sum, 4); sum += __shfl_xor(sum, 8);
            float sc = __expf(m_[i] - mn);
            l_[i] = l_[i] * sc + sum;
            m_[i] = mn;
            scl[i] = sc;
        }
        #pragma unroll
        for (int nf = 0; nf < 4; ++nf)
        #pragma unroll
        for (int i = 0; i < 4; ++i) o[nf][i] *= scl[i];
        __syncthreads();
        #pragma unroll
        for (int nf = 0; nf < 8; ++nf)
        #pragma unroll
        for (int i = 0; i < 4; ++i) {
            int row = wv * 16 + lg * 4 + i;
            int col = nf * 16 + lr;
            Ps[row * 128 + (col ^ ((row & 7) << 3))] = f2b(s[nf][i]);
        }
        #pragma unroll
        for (int ks = 0; ks < 4; ++ks) {
            int row = wv * 16 + lr;
            int kcol = ks * 32 + lg * 8;
            bf16x8 a = *(const bf16x8*)&Ps[row * 128 + (kcol ^ ((row & 7) << 3))];
            int kgt = (kg0 >> 5) + ks;
            #pragma unroll
            for (int nf = 0; nf < 4; ++nf) {
                bf16x8 b = *(const bf16x8*)(VtPk +
                    (((size_t)h * (NPAD/32) + kgt) * 4 + nf) * 512 + (size_t)l * 8);
                o[nf] = MFMA16(a, b, o[nf]);
            }
        }
    }
    const int base = (split * 4 + qt) * 8 + h;
    #pragma unroll
    for (int nf = 0; nf < 4; ++nf)
    #pragma unroll
    for (int i = 0; i < 4; ++i) {
        int r = wv * 16 + lg * 4 + i;
        int c = nf * 16 + lr;
        Opart[((size_t)base * 64 + r) * 64 + c] = o[nf][i];
    }
    if (lr == 0) {
        #pragma unroll
        for (int i = 0; i < 4; ++i) {
            int r = wv * 16 + lg * 4 + i;
            Mpart[base * 64 + r] = m_[i];
            Lpart[base * 64 + r] = l_[i];
        }
    }
}

__global__ __launch_bounds__(256)
void mergeAV_k(const float* __restrict__ Opart, const float* __restrict__ Mpart,
               const float* __restrict__ Lpart, ushort* __restrict__ AVt)
{
    int qt = blockIdx.x, h = blockIdx.y, rq = blockIdx.z;
    int t = threadIdx.x;
    int r = rq * 32 + (t >> 3), c0 = (t & 7) * 8;
    float mv[NSPLIT];
    float mstar = -INFINITY;
    #pragma unroll
    for (int s = 0; s < NSPLIT; ++s) {
        mv[s] = Mpart[((s * 4 + qt) * 8 + h) * 64 + r];
        mstar = fmaxf(mstar, mv[s]);
    }
    float wgt[NSPLIT];
    float L = 0.f;
    #pragma unroll
    for (int s = 0; s < NSPLIT; ++s) {
        wgt[s] = __expf(mv[s] - mstar);
        L += wgt[s] * Lpart[((s * 4 + qt) * 8 + h) * 64 + r];
    }
    float inv = 1.f / L;
    float acc[8] = {};
    #pragma unroll
    for (int s = 0; s < NSPLIT; ++s) {
        const float* op = Opart + (((size_t)(s * 4 + qt) * 8 + h) * 64 + r) * 64 + c0;
        #pragma unroll
        for (int e = 0; e < 8; ++e) acc[e] += wgt[s] * op[e];
    }
    #pragma unroll
    for (int e = 0; e < 8; ++e)
        AVt[((size_t)h * DH + c0 + e) * LM + qt * 64 + r] = f2b(acc[e] * inv);
}

// fused attn1 @ W + conv residual -> OBb
__global__ __launch_bounds__(256, 4)
void outrows64v2(const ushort* __restrict__ Qb, const ushort* __restrict__ KLpk,
                 const ushort* __restrict__ Wpk, const ushort* __restrict__ OBc,
                 ushort* __restrict__ OBb)
{
    __shared__ __align__(16) char smem[40960];
    char*   Qs  = smem;
    ushort* KLs = (ushort*)(smem + 8192);
    ushort* Ps  = (ushort*)(smem + 8192);
    const int tid = threadIdx.x, l = tid & 63, w = tid >> 6;
    const int h = blockIdx.y, i0 = blockIdx.x * 64;
    const int lr = l & 15, lg = l >> 4;

    ushort obc[4][4];
    #pragma unroll
    for (int nf = 0; nf < 4; ++nf)
    #pragma unroll
    for (int i = 0; i < 4; ++i) {
        int r = i0 + w * 16 + lg * 4 + i;
        obc[nf][i] = (r >= PADR)
            ? OBc[(size_t)(r - PADR) * DMODEL + h * DH + nf * 16 + lr] : (ushort)0;
    }
    {
        int row = tid >> 2;
        int seg = (tid & 3) * 32;
        const uint4* src = (const uint4*)(Qb + ((size_t)h * NPAD + i0 + row) * DH) + (tid & 3) * 2;
        uint4 v0 = src[0], v1 = src[1];
        int sw = (row & 7) << 4;
        *(uint4*)(Qs + row * 128 + (seg ^ sw)) = v0;
        *(uint4*)(Qs + row * 128 + ((seg + 16) ^ sw)) = v1;
    }
    {
        const uint4* src = (const uint4*)(KLpk + (size_t)h * 16384) + tid;
        uint4* dst = (uint4*)KLs + tid;
        #pragma unroll
        for (int e = 0; e < 8; ++e) dst[e * 256] = src[e * 256];
    }
    __syncthreads();

    f32x4 s[16];
    #pragma unroll
    for (int nf = 0; nf < 16; ++nf) s[nf] = (f32x4){0.f, 0.f, 0.f, 0.f};
    #pragma unroll
    for (int ks = 0; ks < 2; ++ks) {
        int qrow = w * 16 + lr;
        bf16x8 a = *(const bf16x8*)(Qs + qrow * 128 +
                                    ((ks * 64 + lg * 16) ^ ((qrow & 7) << 4)));
        #pragma unroll
        for (int nf = 0; nf < 16; ++nf) {
            bf16x8 b = *(const bf16x8*)&KLs[((nf * 2 + ks) * 64 + l) * 8];
            s[nf] = MFMA16(a, b, s[nf]);
        }
    }
    float inv_[4];
    #pragma unroll
    for (int i = 0; i < 4; ++i) {
        float m = s[0][i];
        #pragma unroll
        for (int nf = 1; nf < 16; ++nf) m = fmaxf(m, s[nf][i]);
        m = fmaxf(m, __shfl_xor(m, 1)); m = fmaxf(m, __shfl_xor(m, 2));
        m = fmaxf(m, __shfl_xor(m, 4)); m = fmaxf(m, __shfl_xor(m, 8));
        float sum = 0.f;
        #pragma unroll
        for (int nf = 0; nf < 16; ++nf) {
            float e = __expf(s[nf][i] - m); s[nf][i] = e; sum += e;
        }
        sum += __shfl_xor(sum, 1); sum += __shfl_xor(sum, 2);
        sum += __shfl_xor(sum, 4); sum += __shfl_xor(sum, 8);
        inv_[i] = 1.f / sum;
    }
    __syncthreads();
    #pragma unroll
    for (int nf = 0; nf < 16; ++nf)
    #pragma unroll
    for (int i = 0; i < 4; ++i) {
        int row = w * 16 + lg * 4 + i;
        int col = nf * 16 + lr;
        Ps[row * 256 + (col ^ ((row & 7) << 3))] = f2b(s[nf][i] * inv_[i]);
    }
    f32x4 o[4];
    #pragma unroll
    for (int nf = 0; nf < 4; ++nf) o[nf] = (f32x4){0.f, 0.f, 0.f, 0.f};
    #pragma unroll
    for (int ks = 0; ks < 8; ++ks) {
        int row = w * 16 + lr;
        int kcol = ks * 32 + lg * 8;
        bf16x8 a = *(const bf16x8*)&Ps[row * 256 + (kcol ^ ((row & 7) << 3))];
        #pragma unroll
        for (int nf = 0; nf < 4; ++nf) {
            bf16x8 b = *(const bf16x8*)(Wpk + (((size_t)h * 2048) + nf * 512 + ks * 64 + l) * 8);
            o[nf] = MFMA16(a, b, o[nf]);
        }
    }
    #pragma unroll
    for (int nf = 0; nf < 4; ++nf)
    #pragma unroll
    for (int i = 0; i < 4; ++i) {
        int r = i0 + w * 16 + lg * 4 + i;
        if (r >= PADR) {
            int ro = r - PADR;
            int c = h * DH + nf * 16 + lr;
            OBb[(size_t)ro * DMODEL + c] = f2b(o[nf][i] + b2f(obc[nf][i]));
        }
    }
}

// ---------------------------------------------------------------- tail ops
__global__ __launch_bounds__(256)
void edges_k(const int* __restrict__ rows, const int* __restrict__ cols,
             const float* __restrict__ vals,
             const ushort* __restrict__ QE, const ushort* __restrict__ KE,
             float* __restrict__ A_raw, int E)
{
    int gid = blockIdx.x * blockDim.x + threadIdx.x;
    int e = gid >> 4, l = gid & 15;
    if (e >= E) return;
    int r = rows[e], c = cols[e];
    const uint4* qp = (const uint4*)(QE + (size_t)r * DQK + l * 16);
    const uint4* kp = (const uint4*)(KE + (size_t)c * DQK + l * 16);
    float dot = 0.f;
    #pragma unroll
    for (int g = 0; g < 2; ++g) {
        union { uint4 u; ushort s[8]; } qq, kk;
        qq.u = qp[g]; kk.u = kp[g];
        #pragma unroll
        for (int j = 0; j < 8; ++j) dot += b2f(qq.s[j]) * b2f(kk.s[j]);
    }
    dot += __shfl_xor(dot, 8); dot += __shfl_xor(dot, 4);
    dot += __shfl_xor(dot, 2); dot += __shfl_xor(dot, 1);
    if (l == 0) atomicAdd(&A_raw[r], vals[e] * dot * 0.0625f);
}

__global__ __launch_bounds__(256)
void amax_k(const float* __restrict__ A_raw, unsigned int* __restrict__ mx)
{
    __shared__ float red[256];
    int t = threadIdx.x;
    float lm = -INFINITY;
    for (int i = blockIdx.x * 256 + t; i < NSEQ; i += gridDim.x * 256)
        lm = fmaxf(lm, A_raw[i]);
    red[t] = lm; __syncthreads();
    for (int s = 128; s > 0; s >>= 1) { if (t < s) red[t] = fmaxf(red[t], red[t + s]); __syncthreads(); }
    if (t == 0) atomicMax(&mx[2], fenc(red[0]));
}

__global__ __launch_bounds__(256)
void aexp_k(const float* __restrict__ A_raw, const unsigned int* __restrict__ mx,
            float* __restrict__ alpha, float* __restrict__ sum)
{
    __shared__ float red[256];
    int t = threadIdx.x;
    float m = fdec(mx[2]);
    float ls = 0.f;
    for (int i = blockIdx.x * 256 + t; i < NSEQ; i += gridDim.x * 256) {
        float e = __expf(A_raw[i] - m);
        alpha[i] = e;
        ls += e;
    }
    red[t] = ls; __syncthreads();
    for (int s = 128; s > 0; s >>= 1) { if (t < s) red[t] += red[t + s]; __syncthreads(); }
    if (t == 0) atomicAdd(sum, red[0]);
}

__global__ __launch_bounds__(256)
void xo_pooled_k(const ushort* __restrict__ VALb, const ushort* __restrict__ ENCb,
                 const float* __restrict__ alpha, const float* __restrict__ asum,
                 const float* __restrict__ wvb, const float* __restrict__ fck,
                 float* __restrict__ out0)
{
    __shared__ float red[256];
    int t = threadIdx.x;
    float inv_sum = 1.f / asum[0];
    float acc = 0.f;
    const int total = NSEQ * 128;
    for (int idx = blockIdx.x * 256 + t; idx < total; idx += gridDim.x * 256) {
        int r = idx >> 7, dq = (idx & 127) * 4;
        float al = alpha[r] * inv_sum;
        ushort4 v4 = *(const ushort4*)(VALb + (size_t)r * DMODEL + dq);
        ushort4 e4 = *(const ushort4*)(ENCb + (size_t)r * DMODEL + dq);
        float4 b4 = *(const float4*)(wvb + dq);
        float4 f4 = *(const float4*)(fck + dq);
        float vv[4] = {b2f(v4.x) + b4.x, b2f(v4.y) + b4.y,
                       b2f(v4.z) + b4.z, b2f(v4.w) + b4.w};
        float ee[4] = {b2f(e4.x), b2f(e4.y), b2f(e4.z), b2f(e4.w)};
        float ff[4] = {f4.x, f4.y, f4.z, f4.w};
        #pragma unroll
        for (int j = 0; j < 4; ++j) {
            float xl = al * vv[j];
            float s = 1.f / (1.f + __expf(xl));
            float w2 = s * s;
            float xo = 2.f * xl * w2 + 2.f * ee[j] * (1.f - w2);
            acc += xo * ff[j];
        }
    }
    red[t] = acc; __syncthreads();
    for (int s = 128; s > 0; s >>= 1) { if (t < s) red[t] += red[t + s]; __syncthreads(); }
    if (t == 0) atomicAdd(out0, red[0]);
}

// ---------------------------------------------------------------- launch
extern "C" void kernel_launch(void* const* d_in, const int* in_sizes, int n_in,
                              void* d_out, int out_size, void* d_ws, size_t ws_size,
                              hipStream_t stream)
{
    (void)n_in; (void)out_size; (void)ws_size;
    const float* bag   = (const float*)d_in[0];
    const int*   arow  = (const int*)d_in[1];
    const int*   acol  = (const int*)d_in[2];
    const float* aval  = (const float*)d_in[3];
    const float* w_qkv = (const float*)d_in[4];
    const float* w_out = (const float*)d_in[5];
    const float* b_out = (const float*)d_in[6];
    const float* convw = (const float*)d_in[7];
    const float* wq    = (const float*)d_in[8];
    const float* wk    = (const float*)d_in[9];
    const float* wv_w  = (const float*)d_in[10];
    const float* wv_b  = (const float*)d_in[11];
    const float* fck   = (const float*)d_in[15];
    const float* fcb   = (const float*)d_in[16];
    const int E = in_sizes[1];
    float* out = (float*)d_out;

    char* ws = (char*)d_ws;
    size_t off = 0;
    auto alloc = [&](size_t bytes) { void* p = ws + off; off += (bytes + 255) & ~(size_t)255; return p; };
    ushort* Qb    = (ushort*)alloc((size_t)HEADS * NPAD * DH * 2);
    ushort* Kb    = (ushort*)alloc((size_t)HEADS * NPAD * DH * 2);
    ushort* Vb    = (ushort*)alloc((size_t)HEADS * NPAD * DH * 2);
    ushort* bagb  = (ushort*)alloc((size_t)NSEQ * DMODEL * 2);
    ushort* wqkvT = (ushort*)alloc((size_t)2048 * 512 * 2);
    ushort* woutT = (ushort*)alloc((size_t)512 * 512 * 2);
    ushort* wqkT  = (ushort*)alloc((size_t)512 * 512 * 2);
    ushort* VALb  = (ushort*)alloc((size_t)NSEQ * DMODEL * 2);
    ushort* QLb   = (ushort*)alloc((size_t)HEADS * LM * DH * 2);
    ushort* KLb   = (ushort*)alloc((size_t)HEADS * LM * DH * 2);
    ushort* KLpk  = (ushort*)alloc((size_t)HEADS * LM * DH * 2);
    ushort* Wpk   = (ushort*)alloc((size_t)HEADS * DH * LM * 2);
    ushort* X2b   = (ushort*)alloc((size_t)HEADS * LM * LM * 2);
    ushort* Za    = (ushort*)alloc((size_t)HEADS * LM * LM * 2);
    ushort* Zat   = (ushort*)alloc((size_t)HEADS * LM * LM * 2);
    ushort* Zb2   = (ushort*)alloc((size_t)HEADS * LM * LM * 2);
    ushort* Zbt2  = (ushort*)alloc((size_t)HEADS * LM * LM * 2);
    ushort* T0    = (ushort*)alloc((size_t)HEADS * LM * LM * 2);
    ushort* T0t   = (ushort*)alloc((size_t)HEADS * LM * LM * 2);
    ushort* T1t   = (ushort*)alloc((size_t)HEADS * LM * LM * 2);
    ushort* T2t   = (ushort*)alloc((size_t)HEADS * LM * LM * 2);
    ushort* AVt   = (ushort*)alloc((size_t)HEADS * DH * LM * 2);
    ushort* OBc   = (ushort*)alloc((size_t)NSEQ * DMODEL * 2);
    ushort* OBb   = (ushort*)alloc((size_t)NSEQ * DMODEL * 2);
    float*  ENCf  = (float*)alloc((size_t)NSEQ * DMODEL * 4);
    ushort* ENCb  = (ushort*)alloc((size_t)NSEQ * DMODEL * 2);
    float*  ALPHA = (float*)alloc((size_t)NPAD * 4);
    float*  MXf   = (float*)alloc(256);
    unsigned int* MX = (unsigned int*)MXf;
    // aliases (disjoint lifetimes)
    ushort* QEb = Qb;
    ushort* KEb = Kb;
    ushort* VtPk  = (ushort*)ENCf;
    float*  Opart = (float*)ENCb;
    float*  Mpart = (float*)((char*)ENCb + 8388608);
    float*  Lpart = (float*)((char*)ENCb + 8519680);

    // bag convert + output init + weight transposes in ONE launch
    cvtw_k<<<6536, 256, 0, stream>>>(bag, bagb, out, fcb, MX,
                                     w_qkv, w_out, wq, wk, wv_w,
                                     wqkvT, woutT, wqkT);

    // QKV + VAL projection (+ V^T frag-pack), N=2048, TN=128 2-phase dbuf
    mgemm<0, 128><<<1280, 256, 0, stream>>>(
        bagb, wqkvT, NPAD, 2048, 512, PADR, 16,
        Qb, Kb, Vb, VtPk, VALb, nullptr, nullptr);

    // conv residual + Q/K landmarks in one launch
    landconv_k<<<6024, 256, 0, stream>>>(Qb, Kb, Vb, convw, OBc, QLb, KLb, KLpk);

    // attn2 via MFMA (32 blocks)
    attn2m_k<<<dim3(4, HEADS), 256, 0, stream>>>(QLb, KLpk, X2b);
    colrow_k<<<HEADS, 256, 0, stream>>>(X2b, MX);
    zinit_k<<<dim3(LM, HEADS), 256, 0, stream>>>(X2b, MXf, Za, Zat);

    // Newton-Schulz pinv: depth-3 association, 3 launches/iteration (row-split tiles)
    ushort *Z = Za, *Zt = Zat, *Zn = Zb2, *Znt = Zbt2;
    for (int it = 0; it < 6; ++it) {
        pinv_k<true, false, false><<<dim3(4, 16, HEADS), 256, 0, stream>>>(
            X2b, Zt, LM, 0.f, 1.f, T0, T0t);
        ns2_k<<<dim3(4, 32, HEADS), 256, 0, stream>>>(T0, T0t, Z, T1t, T2t);
        ns3_k<<<dim3(4, 16, HEADS), 256, 0, stream>>>(T2t, T1t, Z, Zn, Znt);
        ushort* t;
        t = Z; Z = Zn; Zn = t;
        t = Zt; Zt = Znt; Znt = t;
    }
    // after 6 iterations Z == Za

    // attn3 @ v (flash, split-KV) -> merge -> AVt; W frag-pack directly from GEMM
    attn3_fa<<<dim3(NSPLIT, 4, HEADS), 256, 0, stream>>>(QLb, Kb, VtPk, Opart, Mpart, Lpart);
    mergeAV_k<<<dim3(4, HEADS, 2), 256, 0, stream>>>(Opart, Mpart, Lpart, AVt);
    pinv_k<false, false, true><<<dim3(1, 16, HEADS), 256, 0, stream>>>(
        Za, AVt, DH, 0.f, 1.f, nullptr, Wpk);

    // fused attn1 @ W + conv residual
    outrows64v2<<<dim3(NPAD / 64, HEADS), 256, 0, stream>>>(Qb, KLpk, Wpk, OBc, OBb);

    // enc = out_buf @ w_out + b_out + bag (bf16 residual, bf16-only output)
    mgemm<1, 64><<<632, 256, 0, stream>>>(
        OBb, woutT, NSEQ, DMODEL, 512, 0, 8,
        nullptr, ENCb, nullptr, nullptr, nullptr, b_out, bagb);

    // qe & ke in one GEMM, bf16 outputs
    mgemm<6, 64><<<632, 256, 0, stream>>>(
        ENCb, wqkT, NSEQ, 512, 512, 0, 8,
        QEb, KEb, nullptr, nullptr, nullptr, nullptr, nullptr);

    // sparse edges -> A_raw; alpha max + unnormalized exp/sum
    edges_k<<<(E * 16 + 255) / 256, 256, 0, stream>>>(arow, acol, aval, QEb, KEb, out + 1, E);
    amax_k<<<40, 256, 0, stream>>>(out + 1, MX);
    aexp_k<<<40, 256, 0, stream>>>(out + 1, MX, ALPHA, MXf + 3);

    // fused xo epilogue + pooled reduction (normalization folded in)
    xo_pooled_k<<<1280, 256, 0, stream>>>(VALb, ENCb, ALPHA, MXf + 3, wv_b, fck, out);
}

// Round 23
// 337.593 us; speedup vs baseline: 1.0835x; 1.0835x over previous
//
#include <hip/hip_runtime.h>
#include <hip/hip_bf16.h>
#include <math.h>

#define NSEQ   10000
#define NPAD   10240
#define PADR   240
#define HEADS  8
#define DH     64
#define LM     256
#define LFAC   40
#define DMODEL 512
#define DQK    256
#define OUTSZ  20001
#define NSPLIT 16
#define KCH    128

typedef __attribute__((ext_vector_type(8))) short bf16x8;
typedef __attribute__((ext_vector_type(4))) float f32x4;
#define MFMA16(a,b,c) __builtin_amdgcn_mfma_f32_16x16x32_bf16(a,b,c,0,0,0)

typedef __attribute__((address_space(1))) const unsigned char gconst_t;
typedef __attribute__((address_space(3))) unsigned char lds_t;
#define GLD16(gp, lp) __builtin_amdgcn_global_load_lds((gconst_t*)(gp), (lds_t*)(lp), 16, 0, 0)

__device__ __forceinline__ float b2f(ushort u) {
    return __uint_as_float(((unsigned)u) << 16);
}
__device__ __forceinline__ ushort f2b(float f) {
    unsigned u = __float_as_uint(f);
    unsigned r = (u + 0x7FFFu + ((u >> 16) & 1u)) >> 16;
    return (ushort)r;
}
__device__ __forceinline__ unsigned fenc(float f) {
    unsigned u = __float_as_uint(f);
    return (u & 0x80000000u) ? ~u : (u | 0x80000000u);
}
__device__ __forceinline__ float fdec(unsigned k) {
    return __uint_as_float((k & 0x80000000u) ? (k & 0x7FFFFFFFu) : ~k);
}
__device__ __forceinline__ int swz8(int bid, int nwg) {
    int q = nwg >> 3, r = nwg & 7;
    int x = bid & 7, idx = bid >> 3;
    int start = (x < r) ? x * (q + 1) : r * (q + 1) + (x - r) * q;
    return start + idx;
}
__device__ __forceinline__ f32x4 tr4(f32x4 v, int p) {
    f32x4 u, w;
    float s, r;
    s = (p & 1) ? v[0] : v[1]; r = __shfl_xor(s, 1);
    u[0] = (p & 1) ? r : v[0]; u[1] = (p & 1) ? v[1] : r;
    s = (p & 1) ? v[2] : v[3]; r = __shfl_xor(s, 1);
    u[2] = (p & 1) ? r : v[2]; u[3] = (p & 1) ? v[3] : r;
    s = (p & 2) ? u[0] : u[2]; r = __shfl_xor(s, 2);
    w[0] = (p & 2) ? r : u[0]; w[2] = (p & 2) ? u[2] : r;
    s = (p & 2) ? u[1] : u[3]; r = __shfl_xor(s, 2);
    w[1] = (p & 2) ? r : u[1]; w[3] = (p & 2) ? u[3] : r;
    return w;
}

// ---------------------------------------------------------------- cvt + wtrans + init
// blocks [0,5000): bag fp32->bf16 + output/scalar init
// blocks [5000,6536): weight transposes (wv_w into wqkvT cols 1536..2047)
__global__ __launch_bounds__(256)
void cvtw_k(const float* __restrict__ in, ushort* __restrict__ out,
            float* __restrict__ outbuf, const float* __restrict__ fcb,
            unsigned int* __restrict__ mx,
            const float* __restrict__ w_qkv, const float* __restrict__ w_out,
            const float* __restrict__ wq, const float* __restrict__ wk,
            const float* __restrict__ wv_w,
            ushort* __restrict__ wqkvT, ushort* __restrict__ woutT,
            ushort* __restrict__ wqkT)
{
    __shared__ float tile[32][33];
    int bid = blockIdx.x;
    if (bid < 5000) {
        int i = bid * 256 + threadIdx.x;
        float4 v = ((const float4*)in)[i];
        ushort4 u; u.x = f2b(v.x); u.y = f2b(v.y); u.z = f2b(v.z); u.w = f2b(v.w);
        ((ushort4*)out)[i] = u;
        if (i == 0) {
            outbuf[0] = fcb[0];
            mx[0] = 0u; mx[1] = 0u;
            mx[2] = 0u;
            ((float*)mx)[3] = 0.f;
        }
        if (i >= 1 && i <= NSEQ) outbuf[i] = 0.f;
        if (i >= NSEQ + 1 && i < OUTSZ) outbuf[i] = 1.0f;
    } else {
        int wb = bid - 5000;
        int g0 = (wb % 96) * 32, r0 = (wb / 96) * 32;
        const float* src; ushort* outp; int C; int lc0;
        if (g0 < 1536)      { src = w_qkv; outp = wqkvT;                      C = 1536; lc0 = g0; }
        else if (g0 < 2048) { src = w_out; outp = woutT;                      C = 512;  lc0 = g0 - 1536; }
        else if (g0 < 2304) { src = wq;    outp = wqkT;                       C = 256;  lc0 = g0 - 2048; }
        else if (g0 < 2560) { src = wk;    outp = wqkT + 256*512;             C = 256;  lc0 = g0 - 2304; }
        else                { src = wv_w;  outp = wqkvT + (size_t)1536*512;   C = 512;  lc0 = g0 - 2560; }
        int tx = threadIdx.x & 31, ty = threadIdx.x >> 5;
        for (int i = ty; i < 32; i += 8) tile[i][tx] = src[(size_t)(r0 + i) * C + lc0 + tx];
        __syncthreads();
        for (int i = ty; i < 32; i += 8) outp[(size_t)(lc0 + i) * 512 + r0 + tx] = f2b(tile[tx][i]);
    }
}

// ---------------------------------------------------------------- big MFMA GEMM (BM=128, BN=TN)
template<int MODE, int TN>
__global__ __launch_bounds__(256)
void mgemm(const ushort* __restrict__ A, const ushort* __restrict__ Bt,
           int Mlog, int N, int K, int padr, int nbx,
           void* __restrict__ P0, void* __restrict__ P1, void* __restrict__ P2,
           void* __restrict__ P3, void* __restrict__ P4,
           const float* __restrict__ bias, const ushort* __restrict__ extra)
{
    constexpr int NF = TN / 32;
    constexpr int BSB = TN * 64;
    __shared__ __align__(16) char As[2 * 8192];
    __shared__ __align__(16) char Bs[2 * BSB];
    const int tid = threadIdx.x;
    const int l = tid & 63, w = tid >> 6;
    const int wm = w >> 1, wn = w & 1;
    const int wk_ = swz8(blockIdx.x, gridDim.x);
    const int row0 = (wk_ / nbx) * 128, col0 = (wk_ % nbx) * TN;
    const int lr = l & 15, lg = l >> 4;
    const bool slow = (MODE == 0) && (row0 < padr);
    const int NT = K >> 5;
    f32x4 acc[4][NF];
    #pragma unroll
    for (int i = 0; i < 4; ++i)
        #pragma unroll
        for (int j = 0; j < NF; ++j) acc[i][j] = (f32x4){0.f, 0.f, 0.f, 0.f};

    auto stage = [&](int bf, int t) {
        int k0 = t << 5;
        if (!slow) {
            #pragma unroll
            for (int c = 0; c < 2; ++c) {
                int q = w * 2 + c;
                int row = q * 16 + (l >> 2);
                GLD16(A + (size_t)(row0 + row - padr) * K + k0 + (l & 3) * 8,
                      As + bf * 8192 + q * 1024);
            }
            if (TN == 128) {
                #pragma unroll
                for (int c = 0; c < 2; ++c) {
                    int q = w * 2 + c;
                    int row = q * 16 + (l >> 2);
                    GLD16(Bt + (size_t)(col0 + row) * K + k0 + (l & 3) * 8,
                          Bs + bf * BSB + q * 1024);
                }
            } else {
                int row = w * 16 + (l >> 2);
                GLD16(Bt + (size_t)(col0 + row) * K + k0 + (l & 3) * 8,
                      Bs + bf * BSB + w * 1024);
            }
        } else {
            #pragma unroll
            for (int c = 0; c < 2; ++c) {
                int gidx = c * 256 + tid;
                int row = gidx >> 2, gr = gidx & 3;
                int phys = row0 + row - padr;
                uint4 v = {0, 0, 0, 0};
                if (phys >= 0 && phys < Mlog - padr)
                    v = *(const uint4*)(A + (size_t)phys * K + k0 + gr * 8);
                *(uint4*)(As + bf * 8192 + gidx * 16) = v;
            }
            if (TN == 128) {
                #pragma unroll
                for (int c = 0; c < 2; ++c) {
                    int gidx = c * 256 + tid;
                    int row = gidx >> 2, gr = gidx & 3;
                    *(uint4*)(Bs + bf * BSB + gidx * 16) =
                        *(const uint4*)(Bt + (size_t)(col0 + row) * K + k0 + gr * 8);
                }
            } else {
                int row = tid >> 2, gr = tid & 3;
                *(uint4*)(Bs + bf * BSB + tid * 16) =
                    *(const uint4*)(Bt + (size_t)(col0 + row) * K + k0 + gr * 8);
            }
        }
    };

    int cur = 0;
    stage(0, 0);
    __syncthreads();
    for (int t = 0; t < NT; ++t) {
        if (t + 1 < NT) stage(cur ^ 1, t + 1);
        const char* Ab = As + cur * 8192;
        const char* Bb = Bs + cur * BSB;
        bf16x8 af[4];
        #pragma unroll
        for (int mf = 0; mf < 4; ++mf)
            af[mf] = *(const bf16x8*)(Ab + (wm * 64 + mf * 16 + lr) * 64 + lg * 16);
        #pragma unroll
        for (int nf = 0; nf < NF; ++nf) {
            bf16x8 bfr = *(const bf16x8*)(Bb + (wn * (TN / 2) + nf * 16 + lr) * 64 + lg * 16);
            #pragma unroll
            for (int mf = 0; mf < 4; ++mf)
                acc[mf][nf] = MFMA16(af[mf], bfr, acc[mf][nf]);
        }
        __syncthreads();
        cur ^= 1;
    }

    const int p = lr & 3;
    #pragma unroll
    for (int mf = 0; mf < 4; ++mf)
    #pragma unroll
    for (int nf = 0; nf < NF; ++nf) {
        int cb   = col0 + wn * (TN / 2) + nf * 16 + (lr & 12);
        int rowT = row0 + wm * 64 + mf * 16 + lg * 4 + p;
        if (MODE == 0) {
            int c = col0 + wn * (TN / 2) + nf * 16 + lr;
            if ((c >> 9) == 2) {
                int hh = (c >> 6) & 7;
                int kt  = (row0 + wm * 64 + mf * 16 + lg * 4) >> 5;
                int lgp = ((mf * 2) + (lg >> 1)) & 3;
                int lanep = lr + lgp * 16;
                int e0 = (lg & 1) * 4;
                ushort4 pk;
                pk.x = f2b(acc[mf][nf][0]); pk.y = f2b(acc[mf][nf][1]);
                pk.z = f2b(acc[mf][nf][2]); pk.w = f2b(acc[mf][nf][3]);
                *(ushort4*)&((ushort*)P3)[(((size_t)hh * (NPAD/32) + kt) * 4 + (nf & 3)) * 512
                                          + lanep * 8 + e0] = pk;
            }
            int t = cb >> 9;
            f32x4 v = acc[mf][nf];
            if (t == 0) { v[0] *= 0.125f; v[1] *= 0.125f; v[2] *= 0.125f; v[3] *= 0.125f; }
            f32x4 wv = tr4(v, p);
            ushort4 pk;
            pk.x = f2b(wv[0]); pk.y = f2b(wv[1]); pk.z = f2b(wv[2]); pk.w = f2b(wv[3]);
            if (t < 3) {
                int hh = (cb >> 6) & 7, d0 = cb & 63;
                ushort* dst = (t == 0) ? (ushort*)P0 : (t == 1) ? (ushort*)P1 : (ushort*)P2;
                *(ushort4*)&dst[((size_t)hh * NPAD + rowT) * DH + d0] = pk;
            } else {
                int phys = rowT - PADR;
                if (phys >= 0)
                    *(ushort4*)&((ushort*)P4)[(size_t)phys * DMODEL + (cb & 511)] = pk;
            }
        } else if (MODE == 1) {
            f32x4 wv = tr4(acc[mf][nf], p);
            if (rowT < Mlog) {
                float4 bi = *(const float4*)(bias + cb);
                ushort4 bg = *(const ushort4*)(extra + (size_t)rowT * N + cb);
                float o0 = wv[0] + bi.x + b2f(bg.x), o1 = wv[1] + bi.y + b2f(bg.y);
                float o2 = wv[2] + bi.z + b2f(bg.z), o3 = wv[3] + bi.w + b2f(bg.w);
                ushort4 pk; pk.x = f2b(o0); pk.y = f2b(o1); pk.z = f2b(o2); pk.w = f2b(o3);
                *(ushort4*)&((ushort*)P1)[(size_t)rowT * N + cb] = pk;
            }
        } else if (MODE == 6) {
            f32x4 wv = tr4(acc[mf][nf], p);
            if (rowT < Mlog) {
                ushort4 pk;
                pk.x = f2b(wv[0]); pk.y = f2b(wv[1]); pk.z = f2b(wv[2]); pk.w = f2b(wv[3]);
                if (cb < 256)
                    *(ushort4*)&((ushort*)P0)[(size_t)rowT * 256 + cb] = pk;
                else
                    *(ushort4*)&((ushort*)P1)[(size_t)rowT * 256 + (cb - 256)] = pk;
            }
        }
    }
}

// ---------------------------------------------------------------- pinv one-shot-K GEMM
template<bool PLAIN, bool BCI, bool WPK>
__global__ __launch_bounds__(256)
void pinv_k(const ushort* __restrict__ A, const ushort* __restrict__ Bt,
            int N, float cval, float scale,
            ushort* __restrict__ P0, ushort* __restrict__ P1)
{
    __shared__ __align__(16) char smem[49152];
    char* As = smem;
    char* Bs = smem + 16384;
    const int tid = threadIdx.x, l = tid & 63, w = tid >> 6;
    const int lr = l & 15, lg = l >> 4;
    const int col0 = blockIdx.x * 64, row0 = blockIdx.y * 32, h = blockIdx.z;
    const ushort* Ab = A + (size_t)h * 65536;
    const ushort* Btb = Bt + (size_t)h * ((size_t)N * 256);
    {
        int row = tid >> 3, seg = (tid & 7) * 64;
        const uint4* sa = (const uint4*)(Ab + (size_t)(row0 + row) * 256) + (tid & 7) * 4;
        #pragma unroll
        for (int e = 0; e < 4; ++e) {
            int off = (row * 512 + seg + e * 16) ^ ((row & 7) << 4);
            *(uint4*)(As + off) = sa[e];
        }
    }
    {
        int row = tid >> 2, seg = (tid & 3) * 128;
        const uint4* sb = (const uint4*)(Btb + (size_t)(col0 + row) * 256) + (tid & 3) * 8;
        int gn = col0 + row;
        #pragma unroll
        for (int e = 0; e < 8; ++e) {
            int off = (row * 512 + seg + e * 16) ^ ((row & 7) << 4);
            uint4 vb = sb[e];
            if (BCI) {
                union { uint4 u; ushort s[8]; } t; t.u = vb;
                int gk0 = (seg >> 1) + e * 8;
                #pragma unroll
                for (int j = 0; j < 8; ++j)
                    t.s[j] = f2b(((gn == gk0 + j) ? cval : 0.f) - b2f(t.s[j]));
                vb = t.u;
            }
            *(uint4*)(Bs + off) = vb;
        }
    }
    __syncthreads();
    f32x4 acc[2];
    acc[0] = (f32x4){0.f, 0.f, 0.f, 0.f};
    acc[1] = (f32x4){0.f, 0.f, 0.f, 0.f};
    #pragma unroll
    for (int ks = 0; ks < 8; ++ks) {
        bf16x8 af[2];
        #pragma unroll
        for (int mf = 0; mf < 2; ++mf) {
            int ar = mf * 16 + lr;
            af[mf] = *(const bf16x8*)(As + ((ar * 512 + ks * 64 + lg * 16) ^ ((ar & 7) << 4)));
        }
        int br = w * 16 + lr;
        bf16x8 bf = *(const bf16x8*)(Bs + ((br * 512 + ks * 64 + lg * 16) ^ ((br & 7) << 4)));
        acc[0] = MFMA16(af[0], bf, acc[0]);
        acc[1] = MFMA16(af[1], bf, acc[1]);
    }
    #pragma unroll
    for (int mf = 0; mf < 2; ++mf) {
        int r0v = row0 + mf * 16 + lg * 4;
        int c = col0 + w * 16 + lr;
        if (PLAIN) {
            #pragma unroll
            for (int i = 0; i < 4; ++i)
                P0[(size_t)h * 256 * N + (size_t)(r0v + i) * N + c] = f2b(acc[mf][i] * scale);
        }
        ushort4 pk;
        pk.x = f2b(acc[mf][0] * scale); pk.y = f2b(acc[mf][1] * scale);
        pk.z = f2b(acc[mf][2] * scale); pk.w = f2b(acc[mf][3] * scale);
        if (WPK) {
            int off = (((c >> 4) * 8 + (r0v >> 5)) << 9) + (((r0v >> 3) & 3) << 7)
                    + ((c & 15) << 3) + (r0v & 4);
            *(ushort4*)&P1[(size_t)h * 16384 + off] = pk;
        } else {
            *(ushort4*)&P1[(size_t)h * ((size_t)N * 256) + (size_t)c * 256 + r0v] = pk;
        }
    }
}

// ---------------------------------------------------------------- NS L2: batched pair
__global__ __launch_bounds__(256)
void ns2_k(const ushort* __restrict__ P, const ushort* __restrict__ Pt,
           const ushort* __restrict__ Z,
           ushort* __restrict__ Qt, ushort* __restrict__ V1)
{
    __shared__ __align__(16) char smem[49152];
    char* As = smem;
    char* Bs = smem + 16384;
    const int tid = threadIdx.x, l = tid & 63, w = tid >> 6;
    const int lr = l & 15, lg = l >> 4;
    const int col0 = blockIdx.x * 64;
    const int which = blockIdx.y >> 3;
    const int row0 = (blockIdx.y & 7) * 32;
    const int h = blockIdx.z;
    const ushort* Ab = (which ? Z : P) + (size_t)h * 65536;
    const ushort* Btb = Pt + (size_t)h * 65536;
    {
        int row = tid >> 3, seg = (tid & 7) * 64;
        const uint4* sa = (const uint4*)(Ab + (size_t)(row0 + row) * 256) + (tid & 7) * 4;
        #pragma unroll
        for (int e = 0; e < 4; ++e) {
            int off = (row * 512 + seg + e * 16) ^ ((row & 7) << 4);
            *(uint4*)(As + off) = sa[e];
        }
    }
    {
        int row = tid >> 2, seg = (tid & 3) * 128;
        const uint4* sb = (const uint4*)(Btb + (size_t)(col0 + row) * 256) + (tid & 3) * 8;
        int gn = col0 + row;
        #pragma unroll
        for (int e = 0; e < 8; ++e) {
            int off = (row * 512 + seg + e * 16) ^ ((row & 7) << 4);
            uint4 vb = sb[e];
            if (which == 0) {
                union { uint4 u; ushort s[8]; } t; t.u = vb;
                int gk0 = (seg >> 1) + e * 8;
                #pragma unroll
                for (int j = 0; j < 8; ++j)
                    t.s[j] = f2b(((gn == gk0 + j) ? 7.f : 0.f) - b2f(t.s[j]));
                vb = t.u;
            }
            *(uint4*)(Bs + off) = vb;
        }
    }
    __syncthreads();
    f32x4 acc[2];
    acc[0] = (f32x4){0.f, 0.f, 0.f, 0.f};
    acc[1] = (f32x4){0.f, 0.f, 0.f, 0.f};
    #pragma unroll
    for (int ks = 0; ks < 8; ++ks) {
        bf16x8 af[2];
        #pragma unroll
        for (int mf = 0; mf < 2; ++mf) {
            int ar = mf * 16 + lr;
            af[mf] = *(const bf16x8*)(As + ((ar * 512 + ks * 64 + lg * 16) ^ ((ar & 7) << 4)));
        }
        int br = w * 16 + lr;
        bf16x8 bf = *(const bf16x8*)(Bs + ((br * 512 + ks * 64 + lg * 16) ^ ((br & 7) << 4)));
        acc[0] = MFMA16(af[0], bf, acc[0]);
        acc[1] = MFMA16(af[1], bf, acc[1]);
    }
    #pragma unroll
    for (int mf = 0; mf < 2; ++mf) {
        int r0v = row0 + mf * 16 + lg * 4;
        int c = col0 + w * 16 + lr;
        if (which == 0) {
            ushort4 pk;
            pk.x = f2b(acc[mf][0]); pk.y = f2b(acc[mf][1]);
            pk.z = f2b(acc[mf][2]); pk.w = f2b(acc[mf][3]);
            *(ushort4*)&Qt[(size_t)h * 65536 + (size_t)c * 256 + r0v] = pk;
        } else {
            #pragma unroll
            for (int i = 0; i < 4; ++i)
                V1[(size_t)h * 65536 + (size_t)(r0v + i) * 256 + c] = f2b(acc[mf][i]);
        }
    }
}

// ---------------------------------------------------------------- NS L3
__global__ __launch_bounds__(256)
void ns3_k(const ushort* __restrict__ V1, const ushort* __restrict__ Qt,
           const ushort* __restrict__ Z,
           ushort* __restrict__ Zn, ushort* __restrict__ Znt)
{
    __shared__ __align__(16) char smem[49152];
    char* As = smem;
    char* Bs = smem + 16384;
    const int tid = threadIdx.x, l = tid & 63, w = tid >> 6;
    const int lr = l & 15, lg = l >> 4;
    const int col0 = blockIdx.x * 64, row0 = blockIdx.y * 32, h = blockIdx.z;
    const ushort* Ab = V1 + (size_t)h * 65536;
    const ushort* Btb = Qt + (size_t)h * 65536;
    {
        int row = tid >> 3, seg = (tid & 7) * 64;
        const uint4* sa = (const uint4*)(Ab + (size_t)(row0 + row) * 256) + (tid & 7) * 4;
        #pragma unroll
        for (int e = 0; e < 4; ++e) {
            int off = (row * 512 + seg + e * 16) ^ ((row & 7) << 4);
            *(uint4*)(As + off) = sa[e];
        }
    }
    {
        int row = tid >> 2, seg = (tid & 3) * 128;
        const uint4* sb = (const uint4*)(Btb + (size_t)(col0 + row) * 256) + (tid & 3) * 8;
        #pragma unroll
        for (int e = 0; e < 8; ++e) {
            int off = (row * 512 + seg + e * 16) ^ ((row & 7) << 4);
            *(uint4*)(Bs + off) = sb[e];
        }
    }
    __syncthreads();
    f32x4 acc[2];
    acc[0] = (f32x4){0.f, 0.f, 0.f, 0.f};
    acc[1] = (f32x4){0.f, 0.f, 0.f, 0.f};
    #pragma unroll
    for (int ks = 0; ks < 8; ++ks) {
        bf16x8 af[2];
        #pragma unroll
        for (int mf = 0; mf < 2; ++mf) {
            int ar = mf * 16 + lr;
            af[mf] = *(const bf16x8*)(As + ((ar * 512 + ks * 64 + lg * 16) ^ ((ar & 7) << 4)));
        }
        int br = w * 16 + lr;
        bf16x8 bf = *(const bf16x8*)(Bs + ((br * 512 + ks * 64 + lg * 16) ^ ((br & 7) << 4)));
        acc[0] = MFMA16(af[0], bf, acc[0]);
        acc[1] = MFMA16(af[1], bf, acc[1]);
    }
    #pragma unroll
    for (int mf = 0; mf < 2; ++mf) {
        int r0v = row0 + mf * 16 + lg * 4;
        int c = col0 + w * 16 + lr;
        ushort4 pk;
        #pragma unroll
        for (int i = 0; i < 4; ++i) {
            size_t idx = (size_t)h * 65536 + (size_t)(r0v + i) * 256 + c;
            float o = 0.25f * acc[mf][i] + 3.25f * b2f(Z[idx]) - 3.75f * b2f(V1[idx]);
            ushort u = f2b(o);
            Zn[idx] = u;
            ((ushort*)&pk)[i] = u;
        }
        *(ushort4*)&Znt[(size_t)h * 65536 + (size_t)c * 256 + r0v] = pk;
    }
}

// ---------------------------------------------------------------- conv + landmarks merged
__global__ __launch_bounds__(256)
void landconv_k(const ushort* __restrict__ Qb, const ushort* __restrict__ Kb,
                const ushort* __restrict__ Vb, const float* __restrict__ cw,
                ushort* __restrict__ OBc,
                ushort* __restrict__ QLb, ushort* __restrict__ KLb,
                ushort* __restrict__ KLpk)
{
    int bid = blockIdx.x;
    if (bid < 5000) {
        int idx = bid * 256 + threadIdx.x;
        int ro = idx >> 7, c4 = idx & 127;
        int h = c4 >> 4, dq = (c4 & 15) * 4;
        int i = ro + PADR;
        float a0 = 0, a1 = 0, a2 = 0, a3 = 0;
        #pragma unroll
        for (int tt = 0; tt < 33; ++tt) {
            int src = i + tt - 16;
            if (src < NPAD) {
                float wv = cw[h * 33 + tt];
                ushort4 u = *(const ushort4*)(Vb + ((size_t)h * NPAD + src) * DH + dq);
                a0 += wv * b2f(u.x); a1 += wv * b2f(u.y);
                a2 += wv * b2f(u.z); a3 += wv * b2f(u.w);
            }
        }
        ushort4 o; o.x = f2b(a0); o.y = f2b(a1); o.z = f2b(a2); o.w = f2b(a3);
        *(ushort4*)&OBc[(size_t)ro * DMODEL + h * DH + dq] = o;
    } else {
        int gidx = (bid - 5000) * 4 + (threadIdx.x >> 6);
        int d = threadIdx.x & 63;
        bool isK = gidx >= HEADS * LM;
        int b = isK ? gidx - HEADS * LM : gidx;
        int hh = b >> 8, j = b & 255;
        const ushort* p = (isK ? Kb : Qb) + ((size_t)hh * NPAD + (size_t)j * LFAC) * DH + d;
        float s = 0.f;
        #pragma unroll
        for (int t = 0; t < LFAC; ++t) s += b2f(p[t * DH]);
        ushort u = f2b(s * (1.f / LFAC));
        (isK ? KLb : QLb)[((size_t)hh * LM + j) * DH + d] = u;
        if (isK) {
            int nf = j >> 4, lr = j & 15;
            int ks = d >> 5, lg = (d >> 3) & 3, e = d & 7;
            KLpk[(((size_t)hh * 16 + nf) * 2 + ks) * 512 + (lg * 16 + lr) * 8 + e] = u;
        }
    }
}

// ---------------------------------------------------------------- attn2 via MFMA
__global__ __launch_bounds__(256)
void attn2m_k(const ushort* __restrict__ QLb, const ushort* __restrict__ KLpk,
              ushort* __restrict__ X2b)
{
    __shared__ __align__(16) char smem[40960];
    char*   Qs  = smem;
    ushort* KLs = (ushort*)(smem + 8192);
    const int tid = threadIdx.x, l = tid & 63, w = tid >> 6;
    const int h = blockIdx.y, i0 = blockIdx.x * 64;
    const int lr = l & 15, lg = l >> 4;
    {
        int row = tid >> 2;
        int seg = (tid & 3) * 32;
        const uint4* src = (const uint4*)(QLb + ((size_t)h * LM + i0 + row) * DH) + (tid & 3) * 2;
        uint4 v0 = src[0], v1 = src[1];
        int sw = (row & 7) << 4;
        *(uint4*)(Qs + row * 128 + (seg ^ sw)) = v0;
        *(uint4*)(Qs + row * 128 + ((seg + 16) ^ sw)) = v1;
    }
    {
        const uint4* src = (const uint4*)(KLpk + (size_t)h * 16384) + tid;
        uint4* dst = (uint4*)KLs + tid;
        #pragma unroll
        for (int e = 0; e < 8; ++e) dst[e * 256] = src[e * 256];
    }
    __syncthreads();

    f32x4 s[16];
    #pragma unroll
    for (int nf = 0; nf < 16; ++nf) s[nf] = (f32x4){0.f, 0.f, 0.f, 0.f};
    #pragma unroll
    for (int ks = 0; ks < 2; ++ks) {
        int qrow = w * 16 + lr;
        bf16x8 a = *(const bf16x8*)(Qs + qrow * 128 +
                                    ((ks * 64 + lg * 16) ^ ((qrow & 7) << 4)));
        #pragma unroll
        for (int nf = 0; nf < 16; ++nf) {
            bf16x8 b = *(const bf16x8*)&KLs[((nf * 2 + ks) * 64 + l) * 8];
            s[nf] = MFMA16(a, b, s[nf]);
        }
    }
    float inv_[4];
    #pragma unroll
    for (int i = 0; i < 4; ++i) {
        float m = s[0][i];
        #pragma unroll
        for (int nf = 1; nf < 16; ++nf) m = fmaxf(m, s[nf][i]);
        m = fmaxf(m, __shfl_xor(m, 1)); m = fmaxf(m, __shfl_xor(m, 2));
        m = fmaxf(m, __shfl_xor(m, 4)); m = fmaxf(m, __shfl_xor(m, 8));
        float sum = 0.f;
        #pragma unroll
        for (int nf = 0; nf < 16; ++nf) {
            float e = __expf(s[nf][i] - m); s[nf][i] = e; sum += e;
        }
        sum += __shfl_xor(sum, 1); sum += __shfl_xor(sum, 2);
        sum += __shfl_xor(sum, 4); sum += __shfl_xor(sum, 8);
        inv_[i] = 1.f / sum;
    }
    const int p = lr & 3;
    #pragma unroll
    for (int nf = 0; nf < 16; ++nf) {
        f32x4 v = s[nf];
        v[0] *= inv_[0]; v[1] *= inv_[1]; v[2] *= inv_[2]; v[3] *= inv_[3];
        f32x4 wv = tr4(v, p);
        int rowT = i0 + w * 16 + lg * 4 + p;
        int cb = nf * 16 + (lr & 12);
        ushort4 pk;
        pk.x = f2b(wv[0]); pk.y = f2b(wv[1]); pk.z = f2b(wv[2]); pk.w = f2b(wv[3]);
        *(ushort4*)&X2b[((size_t)h * LM + rowT) * LM + cb] = pk;
    }
}

// only column-sum max needed (row sums of softmax == 1)
__global__ __launch_bounds__(256)
void colrow_k(const ushort* __restrict__ X2b, unsigned int* __restrict__ mx)
{
    int h = blockIdx.x, t = threadIdx.x;
    const ushort* x = X2b + (size_t)h * LM * LM;
    float rs = 0.f;
    for (int i = 0; i < LM; ++i) rs += fabsf(b2f(x[(size_t)i * LM + t]));
    __shared__ float r2[256];
    r2[t] = rs; __syncthreads();
    for (int s = 128; s > 0; s >>= 1) {
        if (t < s) r2[t] = fmaxf(r2[t], r2[t + s]);
        __syncthreads();
    }
    if (t == 0) atomicMax(&mx[1], __float_as_uint(r2[0]));
}

__global__ void zinit_k(const ushort* __restrict__ X2b, const float* __restrict__ mxf,
                        ushort* __restrict__ Z, ushort* __restrict__ Zt)
{
    int i = blockIdx.x, h = blockIdx.y, j = threadIdx.x;
    float scale = 1.f / mxf[1];
    float x = b2f(X2b[((size_t)h * LM + i) * LM + j]) * scale;
    ushort u = f2b(x);
    Z[((size_t)h * LM + j) * LM + i] = u;
    Zt[((size_t)h * LM + i) * LM + j] = u;
}

// ---------------------------------------------------------------- attn3: flash MFMA
__global__ __launch_bounds__(256)
void attn3_fa(const ushort* __restrict__ QLb, const ushort* __restrict__ Kb,
              const ushort* __restrict__ VtPk,
              float* __restrict__ Opart, float* __restrict__ Mpart,
              float* __restrict__ Lpart)
{
    __shared__ __align__(16) char smem[9216 + 18432];
    ushort* Qs = (ushort*)smem;
    ushort* Ks = (ushort*)(smem + 9216);
    ushort* Ps = (ushort*)(smem + 9216);
    const int tid = threadIdx.x, l = tid & 63, wv = tid >> 6;
    const int split = blockIdx.x, qt = blockIdx.y, h = blockIdx.z;
    const int lr = l & 15, lg = l >> 4;
    {
        int row = tid >> 2, seg = (tid & 3) * 16;
        const uint4* src = (const uint4*)(QLb + ((size_t)h * LM + qt * 64 + row) * DH + seg);
        *(uint4*)&Qs[row * 72 + seg] = src[0];
        *(uint4*)&Qs[row * 72 + seg + 8] = src[1];
    }
    f32x4 o[4];
    float m_[4], l_[4];
    #pragma unroll
    for (int nf = 0; nf < 4; ++nf) o[nf] = (f32x4){0.f, 0.f, 0.f, 0.f};
    #pragma unroll
    for (int i = 0; i < 4; ++i) { m_[i] = -INFINITY; l_[i] = 0.f; }
    const int k0base = split * (NPAD / NSPLIT);
    for (int ch = 0; ch < NPAD / NSPLIT / KCH; ++ch) {
        int kg0 = k0base + ch * KCH;
        __syncthreads();
        {
            int row = tid >> 1, half = (tid & 1) * 32;
            const uint4* src = (const uint4*)(Kb + ((size_t)h * NPAD + kg0 + row) * DH + half);
            #pragma unroll
            for (int e = 0; e < 4; ++e) *(uint4*)&Ks[row * 72 + half + e * 8] = src[e];
        }
        __syncthreads();
        f32x4 s[8];
        #pragma unroll
        for (int nf = 0; nf < 8; ++nf) s[nf] = (f32x4){0.f, 0.f, 0.f, 0.f};
        #pragma unroll
        for (int ks = 0; ks < 2; ++ks) {
            bf16x8 a = *(const bf16x8*)&Qs[(wv * 16 + lr) * 72 + ks * 32 + lg * 8];
            #pragma unroll
            for (int nf = 0; nf < 8; ++nf) {
                bf16x8 b = *(const bf16x8*)&Ks[(nf * 16 + lr) * 72 + ks * 32 + lg * 8];
                s[nf] = MFMA16(a, b, s[nf]);
            }
        }
        float scl[4];
        #pragma unroll
        for (int i = 0; i < 4; ++i) {
            float mx = s[0][i];
            #pragma unroll
            for (int nf = 1; nf < 8; ++nf) mx = fmaxf(mx, s[nf][i]);
            mx = fmaxf(mx, __shfl_xor(mx, 1)); mx = fmaxf(mx, __shfl_xor(mx, 2));
            mx = fmaxf(mx, __shfl_xor(mx, 4)); mx = fmaxf(mx, __shfl_xor(mx, 8));
            float mn = fmaxf(m_[i], mx);
            float sum = 0.f;
            #pragma unroll
            for (int nf = 0; nf < 8; ++nf) {
                float e = __expf(s[nf][i] - mn); s[nf][i] = e; sum += e;
            }
            sum += __shfl_xor(sum, 1); sum += __shfl_xor(sum, 2);
            sum += __shfl_xor(sum, 4); sum += __shfl_xor(sum, 8);
            float sc = __expf(m_[i] - mn);
            l_[i] = l_[i] * sc + sum;
            m_[i] = mn;
            scl[i] = sc;
        }
        #pragma unroll
        for (int nf = 0; nf < 4; ++nf)
        #pragma unroll
        for (int i = 0; i < 4; ++i) o[nf][i] *= scl[i];
        __syncthreads();
        #pragma unroll
        for (int nf = 0; nf < 8; ++nf)
        #pragma unroll
        for (int i = 0; i < 4; ++i) {
            int row = wv * 16 + lg * 4 + i;
            int col = nf * 16 + lr;
            Ps[row * 128 + (col ^ ((row & 7) << 3))] = f2b(s[nf][i]);
        }
        #pragma unroll
        for (int ks = 0; ks < 4; ++ks) {
            int row = wv * 16 + lr;
            int kcol = ks * 32 + lg * 8;
            bf16x8 a = *(const bf16x8*)&Ps[row * 128 + (kcol ^ ((row & 7) << 3))];
            int kgt = (kg0 >> 5) + ks;
            #pragma unroll
            for (int nf = 0; nf < 4; ++nf) {
                bf16x8 b = *(const bf16x8*)(VtPk +
                    (((size_t)h * (NPAD/32) + kgt) * 4 + nf) * 512 + (size_t)l * 8);
                o[nf] = MFMA16(a, b, o[nf]);
            }
        }
    }
    const int base = (split * 4 + qt) * 8 + h;
    #pragma unroll
    for (int nf = 0; nf < 4; ++nf)
    #pragma unroll
    for (int i = 0; i < 4; ++i) {
        int r = wv * 16 + lg * 4 + i;
        int c = nf * 16 + lr;
        Opart[((size_t)base * 64 + r) * 64 + c] = o[nf][i];
    }
    if (lr == 0) {
        #pragma unroll
        for (int i = 0; i < 4; ++i) {
            int r = wv * 16 + lg * 4 + i;
            Mpart[base * 64 + r] = m_[i];
            Lpart[base * 64 + r] = l_[i];
        }
    }
}

__global__ __launch_bounds__(256)
void mergeAV_k(const float* __restrict__ Opart, const float* __restrict__ Mpart,
               const float* __restrict__ Lpart, ushort* __restrict__ AVt)
{
    int qt = blockIdx.x, h = blockIdx.y, rq = blockIdx.z;
    int t = threadIdx.x;
    int r = rq * 32 + (t >> 3), c0 = (t & 7) * 8;
    float mv[NSPLIT];
    float mstar = -INFINITY;
    #pragma unroll
    for (int s = 0; s < NSPLIT; ++s) {
        mv[s] = Mpart[((s * 4 + qt) * 8 + h) * 64 + r];
        mstar = fmaxf(mstar, mv[s]);
    }
    float wgt[NSPLIT];
    float L = 0.f;
    #pragma unroll
    for (int s = 0; s < NSPLIT; ++s) {
        wgt[s] = __expf(mv[s] - mstar);
        L += wgt[s] * Lpart[((s * 4 + qt) * 8 + h) * 64 + r];
    }
    float inv = 1.f / L;
    float acc[8] = {};
    #pragma unroll
    for (int s = 0; s < NSPLIT; ++s) {
        const float* op = Opart + (((size_t)(s * 4 + qt) * 8 + h) * 64 + r) * 64 + c0;
        #pragma unroll
        for (int e = 0; e < 8; ++e) acc[e] += wgt[s] * op[e];
    }
    #pragma unroll
    for (int e = 0; e < 8; ++e)
        AVt[((size_t)h * DH + c0 + e) * LM + qt * 64 + r] = f2b(acc[e] * inv);
}

// fused attn1 @ W + conv residual -> OBb
__global__ __launch_bounds__(256, 4)
void outrows64v2(const ushort* __restrict__ Qb, const ushort* __restrict__ KLpk,
                 const ushort* __restrict__ Wpk, const ushort* __restrict__ OBc,
                 ushort* __restrict__ OBb)
{
    __shared__ __align__(16) char smem[40960];
    char*   Qs  = smem;
    ushort* KLs = (ushort*)(smem + 8192);
    ushort* Ps  = (ushort*)(smem + 8192);
    const int tid = threadIdx.x, l = tid & 63, w = tid >> 6;
    const int h = blockIdx.y, i0 = blockIdx.x * 64;
    const int lr = l & 15, lg = l >> 4;

    ushort obc[4][4];
    #pragma unroll
    for (int nf = 0; nf < 4; ++nf)
    #pragma unroll
    for (int i = 0; i < 4; ++i) {
        int r = i0 + w * 16 + lg * 4 + i;
        obc[nf][i] = (r >= PADR)
            ? OBc[(size_t)(r - PADR) * DMODEL + h * DH + nf * 16 + lr] : (ushort)0;
    }
    {
        int row = tid >> 2;
        int seg = (tid & 3) * 32;
        const uint4* src = (const uint4*)(Qb + ((size_t)h * NPAD + i0 + row) * DH) + (tid & 3) * 2;
        uint4 v0 = src[0], v1 = src[1];
        int sw = (row & 7) << 4;
        *(uint4*)(Qs + row * 128 + (seg ^ sw)) = v0;
        *(uint4*)(Qs + row * 128 + ((seg + 16) ^ sw)) = v1;
    }
    {
        const uint4* src = (const uint4*)(KLpk + (size_t)h * 16384) + tid;
        uint4* dst = (uint4*)KLs + tid;
        #pragma unroll
        for (int e = 0; e < 8; ++e) dst[e * 256] = src[e * 256];
    }
    __syncthreads();

    f32x4 s[16];
    #pragma unroll
    for (int nf = 0; nf < 16; ++nf) s[nf] = (f32x4){0.f, 0.f, 0.f, 0.f};
    #pragma unroll
    for (int ks = 0; ks < 2; ++ks) {
        int qrow = w * 16 + lr;
        bf16x8 a = *(const bf16x8*)(Qs + qrow * 128 +
                                    ((ks * 64 + lg * 16) ^ ((qrow & 7) << 4)));
        #pragma unroll
        for (int nf = 0; nf < 16; ++nf) {
            bf16x8 b = *(const bf16x8*)&KLs[((nf * 2 + ks) * 64 + l) * 8];
            s[nf] = MFMA16(a, b, s[nf]);
        }
    }
    float inv_[4];
    #pragma unroll
    for (int i = 0; i < 4; ++i) {
        float m = s[0][i];
        #pragma unroll
        for (int nf = 1; nf < 16; ++nf) m = fmaxf(m, s[nf][i]);
        m = fmaxf(m, __shfl_xor(m, 1)); m = fmaxf(m, __shfl_xor(m, 2));
        m = fmaxf(m, __shfl_xor(m, 4)); m = fmaxf(m, __shfl_xor(m, 8));
        float sum = 0.f;
        #pragma unroll
        for (int nf = 0; nf < 16; ++nf) {
            float e = __expf(s[nf][i] - m); s[nf][i] = e; sum += e;
        }
        sum += __shfl_xor(sum, 1); sum += __shfl_xor(sum, 2);
        sum += __shfl_xor(sum, 4); sum += __shfl_xor(sum, 8);
        inv_[i] = 1.f / sum;
    }
    __syncthreads();
    #pragma unroll
    for (int nf = 0; nf < 16; ++nf)
    #pragma unroll
    for (int i = 0; i < 4; ++i) {
        int row = w * 16 + lg * 4 + i;
        int col = nf * 16 + lr;
        Ps[row * 256 + (col ^ ((row & 7) << 3))] = f2b(s[nf][i] * inv_[i]);
    }
    f32x4 o[4];
    #pragma unroll
    for (int nf = 0; nf < 4; ++nf) o[nf] = (f32x4){0.f, 0.f, 0.f, 0.f};
    #pragma unroll
    for (int ks = 0; ks < 8; ++ks) {
        int row = w * 16 + lr;
        int kcol = ks * 32 + lg * 8;
        bf16x8 a = *(const bf16x8*)&Ps[row * 256 + (kcol ^ ((row & 7) << 3))];
        #pragma unroll
        for (int nf = 0; nf < 4; ++nf) {
            bf16x8 b = *(const bf16x8*)(Wpk + (((size_t)h * 2048) + nf * 512 + ks * 64 + l) * 8);
            o[nf] = MFMA16(a, b, o[nf]);
        }
    }
    #pragma unroll
    for (int nf = 0; nf < 4; ++nf)
    #pragma unroll
    for (int i = 0; i < 4; ++i) {
        int r = i0 + w * 16 + lg * 4 + i;
        if (r >= PADR) {
            int ro = r - PADR;
            int c = h * DH + nf * 16 + lr;
            OBb[(size_t)ro * DMODEL + c] = f2b(o[nf][i] + b2f(obc[nf][i]));
        }
    }
}

// ---------------------------------------------------------------- tail ops
__global__ __launch_bounds__(256)
void edges_k(const int* __restrict__ rows, const int* __restrict__ cols,
             const float* __restrict__ vals,
             const ushort* __restrict__ QE, const ushort* __restrict__ KE,
             float* __restrict__ A_raw, int E)
{
    int gid = blockIdx.x * blockDim.x + threadIdx.x;
    int e = gid >> 4, l = gid & 15;
    if (e >= E) return;
    int r = rows[e], c = cols[e];
    const uint4* qp = (const uint4*)(QE + (size_t)r * DQK + l * 16);
    const uint4* kp = (const uint4*)(KE + (size_t)c * DQK + l * 16);
    float dot = 0.f;
    #pragma unroll
    for (int g = 0; g < 2; ++g) {
        union { uint4 u; ushort s[8]; } qq, kk;
        qq.u = qp[g]; kk.u = kp[g];
        #pragma unroll
        for (int j = 0; j < 8; ++j) dot += b2f(qq.s[j]) * b2f(kk.s[j]);
    }
    dot += __shfl_xor(dot, 8); dot += __shfl_xor(dot, 4);
    dot += __shfl_xor(dot, 2); dot += __shfl_xor(dot, 1);
    if (l == 0) atomicAdd(&A_raw[r], vals[e] * dot * 0.0625f);
}

__global__ __launch_bounds__(256)
void amax_k(const float* __restrict__ A_raw, unsigned int* __restrict__ mx)
{
    __shared__ float red[256];
    int t = threadIdx.x;
    float lm = -INFINITY;
    for (int i = blockIdx.x * 256 + t; i < NSEQ; i += gridDim.x * 256)
        lm = fmaxf(lm, A_raw[i]);
    red[t] = lm; __syncthreads();
    for (int s = 128; s > 0; s >>= 1) { if (t < s) red[t] = fmaxf(red[t], red[t + s]); __syncthreads(); }
    if (t == 0) atomicMax(&mx[2], fenc(red[0]));
}

__global__ __launch_bounds__(256)
void aexp_k(const float* __restrict__ A_raw, const unsigned int* __restrict__ mx,
            float* __restrict__ alpha, float* __restrict__ sum)
{
    __shared__ float red[256];
    int t = threadIdx.x;
    float m = fdec(mx[2]);
    float ls = 0.f;
    for (int i = blockIdx.x * 256 + t; i < NSEQ; i += gridDim.x * 256) {
        float e = __expf(A_raw[i] - m);
        alpha[i] = e;
        ls += e;
    }
    red[t] = ls; __syncthreads();
    for (int s = 128; s > 0; s >>= 1) { if (t < s) red[t] += red[t + s]; __syncthreads(); }
    if (t == 0) atomicAdd(sum, red[0]);
}

__global__ __launch_bounds__(256)
void xo_pooled_k(const ushort* __restrict__ VALb, const ushort* __restrict__ ENCb,
                 const float* __restrict__ alpha, const float* __restrict__ asum,
                 const float* __restrict__ wvb, const float* __restrict__ fck,
                 float* __restrict__ out0)
{
    __shared__ float red[256];
    int t = threadIdx.x;
    float inv_sum = 1.f / asum[0];
    float acc = 0.f;
    const int total = NSEQ * 128;
    for (int idx = blockIdx.x * 256 + t; idx < total; idx += gridDim.x * 256) {
        int r = idx >> 7, dq = (idx & 127) * 4;
        float al = alpha[r] * inv_sum;
        ushort4 v4 = *(const ushort4*)(VALb + (size_t)r * DMODEL + dq);
        ushort4 e4 = *(const ushort4*)(ENCb + (size_t)r * DMODEL + dq);
        float4 b4 = *(const float4*)(wvb + dq);
        float4 f4 = *(const float4*)(fck + dq);
        float vv[4] = {b2f(v4.x) + b4.x, b2f(v4.y) + b4.y,
                       b2f(v4.z) + b4.z, b2f(v4.w) + b4.w};
        float ee[4] = {b2f(e4.x), b2f(e4.y), b2f(e4.z), b2f(e4.w)};
        float ff[4] = {f4.x, f4.y, f4.z, f4.w};
        #pragma unroll
        for (int j = 0; j < 4; ++j) {
            float xl = al * vv[j];
            float s = 1.f / (1.f + __expf(xl));
            float w2 = s * s;
            float xo = 2.f * xl * w2 + 2.f * ee[j] * (1.f - w2);
            acc += xo * ff[j];
        }
    }
    red[t] = acc; __syncthreads();
    for (int s = 128; s > 0; s >>= 1) { if (t < s) red[t] += red[t + s]; __syncthreads(); }
    if (t == 0) atomicAdd(out0, red[0]);
}

// ---------------------------------------------------------------- launch
extern "C" void kernel_launch(void* const* d_in, const int* in_sizes, int n_in,
                              void* d_out, int out_size, void* d_ws, size_t ws_size,
                              hipStream_t stream)
{
    (void)n_in; (void)out_size; (void)ws_size;
    const float* bag   = (const float*)d_in[0];
    const int*   arow  = (const int*)d_in[1];
    const int*   acol  = (const int*)d_in[2];
    const float* aval  = (const float*)d_in[3];
    const float* w_qkv = (const float*)d_in[4];
    const float* w_out = (const float*)d_in[5];
    const float* b_out = (const float*)d_in[6];
    const float* convw = (const float*)d_in[7];
    const float* wq    = (const float*)d_in[8];
    const float* wk    = (const float*)d_in[9];
    const float* wv_w  = (const float*)d_in[10];
    const float* wv_b  = (const float*)d_in[11];
    const float* fck   = (const float*)d_in[15];
    const float* fcb   = (const float*)d_in[16];
    const int E = in_sizes[1];
    float* out = (float*)d_out;

    char* ws = (char*)d_ws;
    size_t off = 0;
    auto alloc = [&](size_t bytes) { void* p = ws + off; off += (bytes + 255) & ~(size_t)255; return p; };
    ushort* Qb    = (ushort*)alloc((size_t)HEADS * NPAD * DH * 2);
    ushort* Kb    = (ushort*)alloc((size_t)HEADS * NPAD * DH * 2);
    ushort* Vb    = (ushort*)alloc((size_t)HEADS * NPAD * DH * 2);
    ushort* bagb  = (ushort*)alloc((size_t)NSEQ * DMODEL * 2);
    ushort* wqkvT = (ushort*)alloc((size_t)2048 * 512 * 2);
    ushort* woutT = (ushort*)alloc((size_t)512 * 512 * 2);
    ushort* wqkT  = (ushort*)alloc((size_t)512 * 512 * 2);
    ushort* VALb  = (ushort*)alloc((size_t)NSEQ * DMODEL * 2);
    ushort* QLb   = (ushort*)alloc((size_t)HEADS * LM * DH * 2);
    ushort* KLb   = (ushort*)alloc((size_t)HEADS * LM * DH * 2);
    ushort* KLpk  = (ushort*)alloc((size_t)HEADS * LM * DH * 2);
    ushort* Wpk   = (ushort*)alloc((size_t)HEADS * DH * LM * 2);
    ushort* X2b   = (ushort*)alloc((size_t)HEADS * LM * LM * 2);
    ushort* Za    = (ushort*)alloc((size_t)HEADS * LM * LM * 2);
    ushort* Zat   = (ushort*)alloc((size_t)HEADS * LM * LM * 2);
    ushort* Zb2   = (ushort*)alloc((size_t)HEADS * LM * LM * 2);
    ushort* Zbt2  = (ushort*)alloc((size_t)HEADS * LM * LM * 2);
    ushort* T0    = (ushort*)alloc((size_t)HEADS * LM * LM * 2);
    ushort* T0t   = (ushort*)alloc((size_t)HEADS * LM * LM * 2);
    ushort* T1t   = (ushort*)alloc((size_t)HEADS * LM * LM * 2);
    ushort* T2t   = (ushort*)alloc((size_t)HEADS * LM * LM * 2);
    ushort* AVt   = (ushort*)alloc((size_t)HEADS * DH * LM * 2);
    ushort* OBc   = (ushort*)alloc((size_t)NSEQ * DMODEL * 2);
    ushort* OBb   = (ushort*)alloc((size_t)NSEQ * DMODEL * 2);
    float*  ENCf  = (float*)alloc((size_t)NSEQ * DMODEL * 4);
    ushort* ENCb  = (ushort*)alloc((size_t)NSEQ * DMODEL * 2);
    float*  ALPHA = (float*)alloc((size_t)NPAD * 4);
    float*  MXf   = (float*)alloc(256);
    unsigned int* MX = (unsigned int*)MXf;
    // aliases (disjoint lifetimes)
    ushort* QEb = Qb;
    ushort* KEb = Kb;
    ushort* VtPk  = (ushort*)ENCf;
    float*  Opart = (float*)ENCb;
    float*  Mpart = (float*)((char*)ENCb + 8388608);
    float*  Lpart = (float*)((char*)ENCb + 8519680);

    // bag convert + output init + weight transposes in ONE launch
    cvtw_k<<<6536, 256, 0, stream>>>(bag, bagb, out, fcb, MX,
                                     w_qkv, w_out, wq, wk, wv_w,
                                     wqkvT, woutT, wqkT);

    // QKV + VAL projection (+ V^T frag-pack), N=2048, TN=128 2-phase dbuf
    mgemm<0, 128><<<1280, 256, 0, stream>>>(
        bagb, wqkvT, NPAD, 2048, 512, PADR, 16,
        Qb, Kb, Vb, VtPk, VALb, nullptr, nullptr);

    // conv residual + Q/K landmarks in one launch
    landconv_k<<<6024, 256, 0, stream>>>(Qb, Kb, Vb, convw, OBc, QLb, KLb, KLpk);

    // attn2 via MFMA (32 blocks)
    attn2m_k<<<dim3(4, HEADS), 256, 0, stream>>>(QLb, KLpk, X2b);
    colrow_k<<<HEADS, 256, 0, stream>>>(X2b, MX);
    zinit_k<<<dim3(LM, HEADS), 256, 0, stream>>>(X2b, MXf, Za, Zat);

    // Newton-Schulz pinv: depth-3 association, 3 launches/iteration
    ushort *Z = Za, *Zt = Zat, *Zn = Zb2, *Znt = Zbt2;
    for (int it = 0; it < 6; ++it) {
        pinv_k<true, false, false><<<dim3(4, 8, HEADS), 256, 0, stream>>>(
            X2b, Zt, LM, 0.f, 1.f, T0, T0t);
        ns2_k<<<dim3(4, 16, HEADS), 256, 0, stream>>>(T0, T0t, Z, T1t, T2t);
        ns3_k<<<dim3(4, 8, HEADS), 256, 0, stream>>>(T2t, T1t, Z, Zn, Znt);
        ushort* t;
        t = Z; Z = Zn; Zn = t;
        t = Zt; Zt = Znt; Znt = t;
    }
    // after 6 iterations Z == Za

    // attn3 @ v (flash, split-KV) -> merge -> AVt; W frag-pack directly from GEMM
    attn3_fa<<<dim3(NSPLIT, 4, HEADS), 256, 0, stream>>>(QLb, Kb, VtPk, Opart, Mpart, Lpart);
    mergeAV_k<<<dim3(4, HEADS, 2), 256, 0, stream>>>(Opart, Mpart, Lpart, AVt);
    pinv_k<false, false, true><<<dim3(1, 8, HEADS), 256, 0, stream>>>(
        Za, AVt, DH, 0.f, 1.f, nullptr, Wpk);

    // fused attn1 @ W + conv residual
    outrows64v2<<<dim3(NPAD / 64, HEADS), 256, 0, stream>>>(Qb, KLpk, Wpk, OBc, OBb);

    // enc = out_buf @ w_out + b_out + bag (bf16 residual, bf16-only output)
    mgemm<1, 64><<<632, 256, 0, stream>>>(
        OBb, woutT, NSEQ, DMODEL, 512, 0, 8,
        nullptr, ENCb, nullptr, nullptr, nullptr, b_out, bagb);

    // qe & ke in one GEMM, bf16 outputs
    mgemm<6, 64><<<632, 256, 0, stream>>>(
        ENCb, wqkT, NSEQ, 512, 512, 0, 8,
        QEb, KEb, nullptr, nullptr, nullptr, nullptr, nullptr);

    // sparse edges -> A_raw; alpha max + unnormalized exp/sum
    edges_k<<<(E * 16 + 255) / 256, 256, 0, stream>>>(arow, acol, aval, QEb, KEb, out + 1, E);
    amax_k<<<40, 256, 0, stream>>>(out + 1, MX);
    aexp_k<<<40, 256, 0, stream>>>(out + 1, MX, ALPHA, MXf + 3);

    // fused xo epilogue + pooled reduction (normalization folded in)
    xo_pooled_k<<<1280, 256, 0, stream>>>(VALb, ENCb, ALPHA, MXf + 3, wv_b, fck, out);
}